// Round 10
// baseline (1379.004 us; speedup 1.0000x reference)
//
#include <hip/hip_runtime.h>
#include <hip/hip_bf16.h>
#include <math.h>

using short8  = __attribute__((ext_vector_type(8))) short;
using half8   = __attribute__((ext_vector_type(8))) _Float16;
using floatx4 = __attribute__((ext_vector_type(4))) float;

static __device__ __forceinline__ float gelu_f(float x) {
    float x3 = x * x * x;
    return 0.5f * x * (1.f + tanhf(0.7978845608028654f * (x + 0.044715f * x3)));
}
static __device__ __forceinline__ short f2h(float f) {
    _Float16 h = (_Float16)f;
    return __builtin_bit_cast(short, h);
}
static __device__ __forceinline__ short f2bf(float f) {
    unsigned u = __float_as_uint(f);
    u += 0x7fffu + ((u >> 16) & 1u);   // RNE
    return (short)(u >> 16);
}
static __device__ __forceinline__ float bf2f(short s) {
    return __uint_as_float(((unsigned)(unsigned short)s) << 16);
}
struct bf3s { short a, b, c; };
static __device__ __forceinline__ bf3s split3(float v) {
    short c0 = f2bf(v); float r = v - bf2f(c0);
    short c1 = f2bf(r); r -= bf2f(c1);
    short c2 = f2bf(r);
    bf3s s; s.a = c0; s.b = c1; s.c = c2; return s;
}

// ============================================================================
// conv1 (C=3): fp32 direct, NHWC fp32 out
// ============================================================================
template <int OCB>
__global__ __launch_bounds__(256) void conv1_nhwc_kernel(
    const float* __restrict__ in1, const float* __restrict__ w,
    const float* __restrict__ bias, float* __restrict__ out, int H, int W, int OC)
{
    int tx = threadIdx.x, ty = threadIdx.y;
    int x = blockIdx.x * 16 + tx, y = blockIdx.y * 16 + ty;
    int oc0 = blockIdx.z * OCB;
    const int C = 3;
    float acc[OCB];
#pragma unroll
    for (int o = 0; o < OCB; ++o) acc[o] = 0.f;
    for (int ic = 0; ic < C; ++ic) {
        const float* src = in1 + (size_t)ic * H * W;
        float v[9];
#pragma unroll
        for (int ky = 0; ky < 3; ++ky) {
            int iy = y + ky - 1;
            bool okY = (iy >= 0) && (iy < H);
#pragma unroll
            for (int kx = 0; kx < 3; ++kx) {
                int ix = x + kx - 1;
                bool ok = okY && (ix >= 0) && (ix < W);
                v[ky * 3 + kx] = ok ? src[(size_t)iy * W + ix] : 0.f;
            }
        }
        const float* wp = w + ((size_t)oc0 * C + ic) * 9;
#pragma unroll
        for (int o = 0; o < OCB; ++o) {
            const float* wo = wp + (size_t)o * C * 9;
            acc[o] += v[0]*wo[0] + v[1]*wo[1] + v[2]*wo[2]
                    + v[3]*wo[3] + v[4]*wo[4] + v[5]*wo[5]
                    + v[6]*wo[6] + v[7]*wo[7] + v[8]*wo[8];
        }
    }
    float* op = out + ((size_t)y * W + x) * OC + oc0;
#pragma unroll
    for (int o = 0; o < OCB; ++o)
        op[o] = fmaxf(acc[o] + bias[oc0 + o], 0.f);
}

// ============================================================================
// maxpools with bf16x3 split outputs (NHWC)
// ============================================================================
__global__ __launch_bounds__(256) void maxpool1_bf3_kernel(
    const float* __restrict__ in, short* __restrict__ o0, short* __restrict__ o1,
    short* __restrict__ o2, int OW, int IW, int C)
{
    int idx = blockIdx.x * 256 + threadIdx.x;
    int g = idx % (C >> 2); int p = idx / (C >> 2);
    int x = p % OW; int y = p / OW;
    size_t base = ((size_t)(2 * y) * IW + 2 * x) * C + g * 4;
    float4 a = *(const float4*)(in + base);
    float4 b = *(const float4*)(in + base + C);
    float4 c = *(const float4*)(in + base + (size_t)IW * C);
    float4 d = *(const float4*)(in + base + (size_t)IW * C + C);
    float v[4];
    v[0] = fmaxf(fmaxf(a.x, b.x), fmaxf(c.x, d.x));
    v[1] = fmaxf(fmaxf(a.y, b.y), fmaxf(c.y, d.y));
    v[2] = fmaxf(fmaxf(a.z, b.z), fmaxf(c.z, d.z));
    v[3] = fmaxf(fmaxf(a.w, b.w), fmaxf(c.w, d.w));
    size_t o = (size_t)p * C + g * 4;
#pragma unroll
    for (int j = 0; j < 4; ++j) {
        bf3s s = split3(v[j]);
        o0[o + j] = s.a; o1[o + j] = s.b; o2[o + j] = s.c;
    }
}

__global__ __launch_bounds__(256) void maxpool2_bf3_kernel(
    const short* __restrict__ i0, const short* __restrict__ i1,
    const short* __restrict__ i2, short* __restrict__ o0, short* __restrict__ o1,
    short* __restrict__ o2, int OW, int IW, int C)
{
    int idx = blockIdx.x * 256 + threadIdx.x;
    int g = idx % (C >> 2); int p = idx / (C >> 2);
    int x = p % OW; int y = p / OW;
    float v[4] = {-1e30f, -1e30f, -1e30f, -1e30f};
#pragma unroll
    for (int dy = 0; dy < 2; ++dy)
#pragma unroll
        for (int dx = 0; dx < 2; ++dx) {
            size_t base = ((size_t)(2 * y + dy) * IW + 2 * x + dx) * C + g * 4;
#pragma unroll
            for (int j = 0; j < 4; ++j) {
                float u = bf2f(i0[base + j]) + bf2f(i1[base + j]) + bf2f(i2[base + j]);
                v[j] = fmaxf(v[j], u);
            }
        }
    size_t o = (size_t)p * C + g * 4;
#pragma unroll
    for (int j = 0; j < 4; ++j) {
        bf3s s = split3(v[j]);
        o0[o + j] = s.a; o1[o + j] = s.b; o2[o + j] = s.c;
    }
}

// ============================================================================
// pack conv weights -> 3 bf16 planes, k = (ky*3+kx)*C + c
// ============================================================================
__global__ void pack_conv3_kernel(const float* __restrict__ w,
                                  short* __restrict__ B0, short* __restrict__ B1,
                                  short* __restrict__ B2, int C, int OC, int total)
{
    int t = blockIdx.x * 256 + threadIdx.x;
    if (t >= total) return;
    int lane = t & 63, fi = t >> 6;
    int NT = OC >> 4;
    int nt = fi % NT, kt = fi / NT;
    int cpt = C >> 5;
    int tap = kt / cpt, ct = kt % cpt;
    int c = ct * 32 + (lane >> 4) * 8;
    int oc = nt * 16 + (lane & 15);
    short8 v0, v1, v2;
#pragma unroll
    for (int j = 0; j < 8; ++j) {
        bf3s s = split3(w[((size_t)oc * C + c + j) * 9 + tap]);
        v0[j] = s.a; v1[j] = s.b; v2[j] = s.c;
    }
    ((short8*)B0)[t] = v0; ((short8*)B1)[t] = v1; ((short8*)B2)[t] = v2;
}

// ============================================================================
// bf16x3 implicit-GEMM 3x3 conv (conv2/conv3) — R9-proven
// ============================================================================
__global__ __launch_bounds__(256) void conv_bf3_kernel(
    const short* __restrict__ ia0, const short* __restrict__ ia1,
    const short* __restrict__ ia2,
    const short* __restrict__ B0, const short* __restrict__ B1,
    const short* __restrict__ B2, const float* __restrict__ bias,
    float* __restrict__ outf, short* __restrict__ o0, short* __restrict__ o1,
    short* __restrict__ o2, short* __restrict__ oh,
    int H, int W, int C, int OC)
{
    int tid = threadIdx.x, wave = tid >> 6, lane = tid & 63;
    int quad = lane >> 4, l16 = lane & 15;
    int x0 = blockIdx.x * 64, y = blockIdx.y, nt0 = blockIdx.z * 4;
    int cpt = C >> 5, NT = OC >> 4;
    const short8* b0p = (const short8*)B0;
    const short8* b1p = (const short8*)B1;
    const short8* b2p = (const short8*)B2;
    floatx4 aM[4] = {{0,0,0,0},{0,0,0,0},{0,0,0,0},{0,0,0,0}};
    floatx4 aC[4] = {{0,0,0,0},{0,0,0,0},{0,0,0,0},{0,0,0,0}};
    int xm = x0 + wave * 16 + l16;
    for (int ky = 0; ky < 3; ++ky) {
        int yy = y + ky - 1;
        bool rok = (yy >= 0) && (yy < H);
        for (int kx = 0; kx < 3; ++kx) {
            int xx = xm + kx - 1;
            bool ok = rok && (xx >= 0) && (xx < W);
            size_t pos = (size_t)yy * W + xx;
            int ktb = (ky * 3 + kx) * cpt;
            for (int ct = 0; ct < cpt; ++ct) {
                int cc = ct * 32 + quad * 8;
                short8 A0 = {0,0,0,0,0,0,0,0}, A1 = A0, A2 = A0;
                if (ok) {
                    A0 = *(const short8*)(ia0 + pos * C + cc);
                    A1 = *(const short8*)(ia1 + pos * C + cc);
                    A2 = *(const short8*)(ia2 + pos * C + cc);
                }
                size_t bi = ((size_t)(ktb + ct) * NT + nt0) * 64 + lane;
#pragma unroll
                for (int s = 0; s < 4; ++s) {
                    short8 w0 = b0p[bi + s * 64];
                    short8 w1 = b1p[bi + s * 64];
                    short8 w2 = b2p[bi + s * 64];
                    aM[s] = __builtin_amdgcn_mfma_f32_16x16x32_bf16(A0, w0, aM[s], 0, 0, 0);
                    aC[s] = __builtin_amdgcn_mfma_f32_16x16x32_bf16(A0, w1, aC[s], 0, 0, 0);
                    aC[s] = __builtin_amdgcn_mfma_f32_16x16x32_bf16(A1, w0, aC[s], 0, 0, 0);
                    aC[s] = __builtin_amdgcn_mfma_f32_16x16x32_bf16(A0, w2, aC[s], 0, 0, 0);
                    aC[s] = __builtin_amdgcn_mfma_f32_16x16x32_bf16(A1, w1, aC[s], 0, 0, 0);
                    aC[s] = __builtin_amdgcn_mfma_f32_16x16x32_bf16(A2, w0, aC[s], 0, 0, 0);
                }
            }
        }
    }
#pragma unroll
    for (int s = 0; s < 4; ++s) {
        int n = (nt0 + s) * 16 + l16;
        float bs = bias[n];
#pragma unroll
        for (int r = 0; r < 4; ++r) {
            int m = wave * 16 + quad * 4 + r;
            int x = x0 + m;
            float v = fmaxf(aM[s][r] + aC[s][r] + bs, 0.f);
            size_t o = ((size_t)y * W + x) * OC + n;
            if (outf) outf[o] = v;
            else {
                bf3s sp = split3(v);
                o0[o] = sp.a; o1[o] = sp.b; o2[o] = sp.c;
                oh[o] = f2h(v);
            }
        }
    }
}

// ============================================================================
// LayerNorm: fp32 math, bf16x3 plane outputs
// ============================================================================
__global__ __launch_bounds__(256) void ln_bf3_kernel(
    const float* __restrict__ x, const float* __restrict__ g,
    const float* __restrict__ b, short* __restrict__ y0,
    short* __restrict__ y1, short* __restrict__ y2)
{
    int wave = threadIdx.x >> 6, lane = threadIdx.x & 63;
    int n = blockIdx.x * 4 + wave;
    const float* xr = x + (size_t)n * 256;
    float4 v = *(const float4*)(xr + lane * 4);
    float s = v.x + v.y + v.z + v.w;
#pragma unroll
    for (int m = 1; m < 64; m <<= 1) s += __shfl_xor(s, m);
    float mean = s * (1.f / 256.f);
    float cx = v.x - mean, cy = v.y - mean, cz = v.z - mean, cw = v.w - mean;
    float q = cx * cx + cy * cy + cz * cz + cw * cw;
#pragma unroll
    for (int m = 1; m < 64; m <<= 1) q += __shfl_xor(q, m);
    float rstd = rsqrtf(q * (1.f / 256.f) + 1e-5f);
    float4 gv = *(const float4*)(g + lane * 4);
    float4 bv = *(const float4*)(b + lane * 4);
    float o[4];
    o[0] = cx * rstd * gv.x + bv.x;
    o[1] = cy * rstd * gv.y + bv.y;
    o[2] = cz * rstd * gv.z + bv.z;
    o[3] = cw * rstd * gv.w + bv.w;
    size_t ob = (size_t)n * 256 + lane * 4;
#pragma unroll
    for (int j = 0; j < 4; ++j) {
        bf3s sp = split3(o[j]);
        y0[ob + j] = sp.a; y1[ob + j] = sp.b; y2[ob + j] = sp.c;
    }
}

// ============================================================================
// fused bucket + knorm (fp32, bucket-critical)
// ============================================================================
__global__ __launch_bounds__(256) void bucketn_kernel(
    const float* __restrict__ qk, const float* __restrict__ rot,
    int* __restrict__ buckets, float* __restrict__ knrm)
{
    int t = blockIdx.x * 256 + threadIdx.x;
    int h = t >> 12, n = t & 4095;
    const float* q = qk + (size_t)n * 256 + h * 64;
    const float* R = rot + (size_t)h * 2048;
    float acc[32];
#pragma unroll
    for (int r = 0; r < 32; ++r) acc[r] = 0.f;
    float s2 = 0.f;
    for (int d = 0; d < 64; ++d) {
        float qd = q[d];
        s2 += qd * qd;
        const float* Rd = R + d * 32;
#pragma unroll
        for (int r = 0; r < 32; ++r) acc[r] += qd * Rd[r];
    }
    knrm[t] = 1.f / (sqrtf(s2) + 1e-6f);
    float bvv = acc[0]; int best = 0;
#pragma unroll
    for (int j = 1; j < 64; ++j) {
        float val = (j < 32) ? acc[j] : -acc[j - 32];
        if (val > bvv) { bvv = val; best = j; }
    }
    buckets[t] = best;
}

__global__ __launch_bounds__(256) void lsh_sort_kernel(
    const int* __restrict__ buckets, int* __restrict__ perm)
{
    int h = blockIdx.x;
    const int* bk = buckets + h * 4096;
    __shared__ unsigned long long mask[64][64];
    __shared__ int counts[64];
    __shared__ int offsets[64];
    __shared__ int wpre[64][64];
    int tid = threadIdx.x, wave = tid >> 6, lane = tid & 63;
    for (int w = wave * 16; w < wave * 16 + 16; ++w) {
        int bl = bk[w * 64 + lane];
        for (int b = 0; b < 64; ++b) {
            unsigned long long m = __ballot(bl == b);
            if (lane == b) mask[b][w] = m;
        }
    }
    __syncthreads();
    if (tid < 64) {
        int c = 0;
        for (int w = 0; w < 64; ++w) c += __popcll(mask[tid][w]);
        counts[tid] = c;
    }
    __syncthreads();
    if (tid == 0) {
        int a = 0;
        for (int b = 0; b < 64; ++b) { offsets[b] = a; a += counts[b]; }
    }
    __syncthreads();
    for (int b = wave * 16; b < wave * 16 + 16; ++b) {
        int c = __popcll(mask[b][lane]);
        int incl = c;
#pragma unroll
        for (int off = 1; off < 64; off <<= 1) {
            int nb = __shfl_up(incl, off);
            if (lane >= off) incl += nb;
        }
        wpre[b][lane] = incl - c + offsets[b];
    }
    __syncthreads();
    for (int i = tid; i < 4096; i += 256) {
        int b = bk[i]; int w = i >> 6; int l = i & 63;
        unsigned long long below = mask[b][w] & ((1ull << l) - 1ull);
        int pos = wpre[b][w] + __popcll(below);
        perm[h * 4096 + pos] = i;
    }
}

// attention: fp32 math, bf16x3 plane outputs
__global__ __launch_bounds__(256) void attn_kernel(
    const float* __restrict__ qk, const float* __restrict__ vv,
    const float* __restrict__ knrm, const int* __restrict__ perm,
    short* __restrict__ o0, short* __restrict__ o1, short* __restrict__ o2)
{
    __shared__ float ks[128 * 64];
    __shared__ float dotsT[128 * 64];
    int c = blockIdx.x, h = blockIdx.y;
    int tid = threadIdx.x;
    const int* pm = perm + h * 4096;
    int cm = (c + 63) & 63;
    {
        int jr = tid >> 1, hf = tid & 1;
        int sk = (jr < 64) ? (c * 64 + jr) : (cm * 64 + (jr - 64));
        int nk = pm[sk];
        float sc = knrm[h * 4096 + nk];
        const float* src = qk + (size_t)nk * 256 + h * 64 + hf * 32;
        float* dst = ks + jr * 64 + hf * 32;
#pragma unroll
        for (int d = 0; d < 32; d += 4) {
            float4 v = *(const float4*)(src + d);
            v.x *= sc; v.y *= sc; v.z *= sc; v.w *= sc;
            *(float4*)(dst + d) = v;
        }
    }
    __syncthreads();
    int r = tid & 63, jg = tid >> 6;
    int nq = pm[c * 64 + r];
    {
        float qreg[64];
        const float* src = qk + (size_t)nq * 256 + h * 64;
#pragma unroll
        for (int d = 0; d < 64; d += 4) {
            float4 v = *(const float4*)(src + d);
            qreg[d] = v.x; qreg[d + 1] = v.y; qreg[d + 2] = v.z; qreg[d + 3] = v.w;
        }
        for (int j = jg * 32; j < jg * 32 + 32; ++j) {
            const float* kr = ks + j * 64;
            float dot = 0.f;
#pragma unroll
            for (int d = 0; d < 64; ++d) dot += qreg[d] * kr[d];
            int sk = (j < 64) ? (c * 64 + j) : (cm * 64 + (j - 64));
            int nk = pm[sk];
            dot = (nk == nq) ? -1e5f : dot * 0.125f;
            dotsT[j * 64 + r] = dot;
        }
    }
    __syncthreads();
    {
        int jr = tid >> 1, hf = tid & 1;
        int sk = (jr < 64) ? (c * 64 + jr) : (cm * 64 + (jr - 64));
        int nk = pm[sk];
        const float* src = vv + (size_t)nk * 256 + h * 64 + hf * 32;
        float* dst = ks + jr * 64 + hf * 32;
#pragma unroll
        for (int d = 0; d < 32; d += 4)
            *(float4*)(dst + d) = *(const float4*)(src + d);
    }
    if (tid < 64) {
        int rr = tid;
        float mx = -1e30f;
        for (int j = 0; j < 128; ++j) mx = fmaxf(mx, dotsT[j * 64 + rr]);
        float s = 0.f;
        for (int j = 0; j < 128; ++j) {
            float e = expf(dotsT[j * 64 + rr] - mx);
            dotsT[j * 64 + rr] = e; s += e;
        }
        float inv = 1.f / s;
        for (int j = 0; j < 128; ++j) dotsT[j * 64 + rr] *= inv;
    }
    __syncthreads();
    int dg = jg;
    float acc[16];
#pragma unroll
    for (int d = 0; d < 16; ++d) acc[d] = 0.f;
    for (int j = 0; j < 128; ++j) {
        float a = dotsT[j * 64 + r];
        const float* vr = ks + j * 64 + dg * 16;
#pragma unroll
        for (int d = 0; d < 16; ++d) acc[d] += a * vr[d];
    }
    size_t ob = (size_t)nq * 256 + h * 64 + dg * 16;
#pragma unroll
    for (int d = 0; d < 16; ++d) {
        bf3s sp = split3(acc[d]);
        o0[ob + d] = sp.a; o1[ob + d] = sp.b; o2[ob + d] = sp.c;
    }
}

// ============================================================================
// fused per-layer weight pack: 5 matrices -> 15 bf16 fragment planes
// ============================================================================
static __device__ __forceinline__ void pack_one(
    const float* __restrict__ W, short* __restrict__ B0, short* __restrict__ B1,
    short* __restrict__ B2, int N, int t)
{
    int lane = t & 63, fi = t >> 6;
    int NT = N >> 4;
    int nt = fi % NT, kt = fi / NT;
    int n = nt * 16 + (lane & 15);
    int k0 = kt * 32 + (lane >> 4) * 8;
    short8 v0, v1, v2;
#pragma unroll
    for (int j = 0; j < 8; ++j) {
        bf3s s = split3(W[(size_t)(k0 + j) * N + n]);
        v0[j] = s.a; v1[j] = s.b; v2[j] = s.c;
    }
    ((short8*)B0)[t] = v0; ((short8*)B1)[t] = v1; ((short8*)B2)[t] = v2;
}

__global__ void pack_layer_kernel(
    const float* __restrict__ Wqk, const float* __restrict__ Wv,
    const float* __restrict__ Wo, const float* __restrict__ Wff1,
    const float* __restrict__ Wff2,
    short* q0, short* q1, short* q2, short* v0, short* v1, short* v2,
    short* o0, short* o1, short* o2, short* f10, short* f11, short* f12,
    short* f20, short* f21, short* f22)
{
    int t = blockIdx.x * 256 + threadIdx.x;
    if (t < 8192)       pack_one(Wqk, q0, q1, q2, 256, t);
    else if (t < 16384) pack_one(Wv, v0, v1, v2, 256, t - 8192);
    else if (t < 24576) pack_one(Wo, o0, o1, o2, 256, t - 16384);
    else if (t < 57344) pack_one(Wff1, f10, f11, f12, 1024, t - 24576);
    else if (t < 90112) pack_one(Wff2, f20, f21, f22, 256, t - 57344);
}

// ============================================================================
// bf16x3 GEMM v2: per-wave N=32 tile, register prefetch, dual correction acc.
// A as 3 bf16 planes. out fp32 (+resid) or 3 bf16 planes.
// ============================================================================
static __device__ __forceinline__ void gemm_bf3_core(
    const short* __restrict__ A0, const short* __restrict__ A1,
    const short* __restrict__ A2,
    const short* __restrict__ B0, const short* __restrict__ B1,
    const short* __restrict__ B2, const float* __restrict__ bias,
    float* __restrict__ Cf, short* __restrict__ D0, short* __restrict__ D1,
    short* __restrict__ D2, int N, int K, int act, int resid, int bx, int by)
{
    int tid = threadIdx.x, wave = tid >> 6, lane = tid & 63;
    int quad = lane >> 4, l16 = lane & 15;
    int m0 = by * 64 + wave * 16;
    int NT = N >> 4, nt0 = bx * 2;
    size_t arow = (size_t)(m0 + l16) * K + quad * 8;
    const short8* b0p = (const short8*)B0;
    const short8* b1p = (const short8*)B1;
    const short8* b2p = (const short8*)B2;
    floatx4 aM0 = {0,0,0,0}, aM1 = {0,0,0,0};
    floatx4 aC10 = {0,0,0,0}, aC11 = {0,0,0,0};
    floatx4 aC20 = {0,0,0,0}, aC21 = {0,0,0,0};
    int KT = K >> 5;
    size_t bi0 = (size_t)nt0 * 64 + lane;
    short8 a0 = *(const short8*)(A0 + arow);
    short8 a1 = *(const short8*)(A1 + arow);
    short8 a2 = *(const short8*)(A2 + arow);
    short8 w00 = b0p[bi0], w01 = b1p[bi0], w02 = b2p[bi0];
    short8 w10 = b0p[bi0 + 64], w11 = b1p[bi0 + 64], w12 = b2p[bi0 + 64];
    for (int kt = 0; kt < KT; ++kt) {
        short8 na0 = {}, na1 = {}, na2 = {};
        short8 nw00 = {}, nw01 = {}, nw02 = {}, nw10 = {}, nw11 = {}, nw12 = {};
        if (kt + 1 < KT) {
            size_t ar = arow + (size_t)(kt + 1) * 32;
            na0 = *(const short8*)(A0 + ar);
            na1 = *(const short8*)(A1 + ar);
            na2 = *(const short8*)(A2 + ar);
            size_t nbi = ((size_t)(kt + 1) * NT + nt0) * 64 + lane;
            nw00 = b0p[nbi]; nw01 = b1p[nbi]; nw02 = b2p[nbi];
            nw10 = b0p[nbi + 64]; nw11 = b1p[nbi + 64]; nw12 = b2p[nbi + 64];
        }
        aM0  = __builtin_amdgcn_mfma_f32_16x16x32_bf16(a0, w00, aM0, 0, 0, 0);
        aM1  = __builtin_amdgcn_mfma_f32_16x16x32_bf16(a0, w10, aM1, 0, 0, 0);
        aC10 = __builtin_amdgcn_mfma_f32_16x16x32_bf16(a0, w01, aC10, 0, 0, 0);
        aC11 = __builtin_amdgcn_mfma_f32_16x16x32_bf16(a0, w11, aC11, 0, 0, 0);
        aC20 = __builtin_amdgcn_mfma_f32_16x16x32_bf16(a1, w00, aC20, 0, 0, 0);
        aC21 = __builtin_amdgcn_mfma_f32_16x16x32_bf16(a1, w10, aC21, 0, 0, 0);
        aC10 = __builtin_amdgcn_mfma_f32_16x16x32_bf16(a0, w02, aC10, 0, 0, 0);
        aC11 = __builtin_amdgcn_mfma_f32_16x16x32_bf16(a0, w12, aC11, 0, 0, 0);
        aC20 = __builtin_amdgcn_mfma_f32_16x16x32_bf16(a1, w01, aC20, 0, 0, 0);
        aC21 = __builtin_amdgcn_mfma_f32_16x16x32_bf16(a1, w11, aC21, 0, 0, 0);
        aC10 = __builtin_amdgcn_mfma_f32_16x16x32_bf16(a2, w00, aC10, 0, 0, 0);
        aC11 = __builtin_amdgcn_mfma_f32_16x16x32_bf16(a2, w10, aC11, 0, 0, 0);
        a0 = na0; a1 = na1; a2 = na2;
        w00 = nw00; w01 = nw01; w02 = nw02;
        w10 = nw10; w11 = nw11; w12 = nw12;
    }
    floatx4 aM[2] = {aM0, aM1};
    floatx4 c1[2] = {aC10, aC11};
    floatx4 c2[2] = {aC20, aC21};
#pragma unroll
    for (int s = 0; s < 2; ++s) {
        int n = (nt0 + s) * 16 + l16;
        float bs = bias[n];
#pragma unroll
        for (int r = 0; r < 4; ++r) {
            int m = m0 + quad * 4 + r;
            float v = aM[s][r] + (c1[s][r] + c2[s][r]) + bs;
            if (act == 1) v = gelu_f(v);
            size_t o = (size_t)m * N + n;
            if (D0) {
                bf3s sp = split3(v);
                D0[o] = sp.a; D1[o] = sp.b; D2[o] = sp.c;
            } else {
                if (resid) v += Cf[o];
                Cf[o] = v;
            }
        }
    }
}

__global__ __launch_bounds__(256) void gemm_bf3_kernel(
    const short* A0, const short* A1, const short* A2,
    const short* B0, const short* B1, const short* B2,
    const float* bias, float* Cf, short* D0, short* D1, short* D2,
    int N, int K, int act, int resid)
{
    gemm_bf3_core(A0, A1, A2, B0, B1, B2, bias, Cf, D0, D1, D2,
                  N, K, act, resid, blockIdx.x, blockIdx.y);
}

// fused QK|V (N=256 each): blocks x<8 -> QK, else V
__global__ __launch_bounds__(256) void gemm_qkv_bf3_kernel(
    const short* A0, const short* A1, const short* A2,
    const short* Q0, const short* Q1, const short* Q2,
    const float* qb, float* Cq,
    const short* V0, const short* V1, const short* V2,
    const float* vb, float* Cv, int K)
{
    int side = blockIdx.x >> 3;
    gemm_bf3_core(A0, A1, A2, side ? V0 : Q0, side ? V1 : Q1, side ? V2 : Q2,
                  side ? vb : qb, side ? Cv : Cq, nullptr, nullptr, nullptr,
                  256, K, 0, 0, blockIdx.x & 7, blockIdx.y);
}

// ============================================================================
// plain fp16 MFMA decoder kernels (R8-proven)
// ============================================================================
__global__ void pack_conv_kernel(const float* __restrict__ w, short* __restrict__ Bp,
                                 int C, int OC, int NT, int total)
{
    int t = blockIdx.x * 256 + threadIdx.x;
    if (t >= total) return;
    int lane = t & 63, fi = t >> 6;
    int nt = fi % NT, kt = fi / NT;
    int cpt = C >> 5;
    int tap = kt / cpt, ct = kt % cpt;
    int c = ct * 32 + (lane >> 4) * 8;
    int oc = nt * 16 + (lane & 15);
    short8 v;
#pragma unroll
    for (int j = 0; j < 8; ++j) {
        float f = (oc < OC) ? w[((size_t)oc * C + c + j) * 9 + tap] : 0.f;
        v[j] = f2h(f);
    }
    ((short8*)Bp)[t] = v;
}

__global__ void pack_convt_kernel(const float* __restrict__ w, short* __restrict__ Bp,
                                  int IC, int OC, int total)
{
    int t = blockIdx.x * 256 + threadIdx.x;
    if (t >= total) return;
    int lane = t & 63, fi = t >> 6;
    int NT = OC >> 4, cpt = IC >> 5, KT4 = 4 * cpt;
    int nt = fi % NT, r = fi / NT;
    int kt = r % KT4, pz = r / KT4;
    int py = pz >> 1, px = pz & 1;
    int t4 = kt / cpt, ct = kt % cpt;
    int ty = t4 >> 1, tx = t4 & 1;
    int ky = py ? (2 * ty) : (1 + 2 * ty);
    int kx = px ? (2 * tx) : (1 + 2 * tx);
    int ic = ct * 32 + (lane >> 4) * 8;
    int oc = nt * 16 + (lane & 15);
    short8 v;
#pragma unroll
    for (int j = 0; j < 8; ++j)
        v[j] = f2h(w[(((size_t)(ic + j) * OC + oc) * 4 + ky) * 4 + kx]);
    ((short8*)Bp)[t] = v;
}

__global__ __launch_bounds__(256) void conv_mfma_kernel(
    const short* __restrict__ in1, int C1, const short* __restrict__ in2, int C2,
    const short* __restrict__ Bp, const float* __restrict__ bias,
    short* __restrict__ outb, int H, int W, int OC)
{
    int tid = threadIdx.x, wave = tid >> 6, lane = tid & 63;
    int quad = lane >> 4, l16 = lane & 15;
    int x0 = blockIdx.x * 64, y = blockIdx.y, nt0 = blockIdx.z * 4;
    int C = C1 + C2, cpt = C >> 5, NT = OC >> 4;
    const half8* bp = (const half8*)Bp;
    floatx4 acc[4] = {{0,0,0,0},{0,0,0,0},{0,0,0,0},{0,0,0,0}};
    int xm = x0 + wave * 16 + l16;
    for (int ky = 0; ky < 3; ++ky) {
        int yy = y + ky - 1;
        bool rok = (yy >= 0) && (yy < H);
        for (int kx = 0; kx < 3; ++kx) {
            int xx = xm + kx - 1;
            bool ok = rok && (xx >= 0) && (xx < W);
            size_t pos = (size_t)yy * W + xx;
            int ktb = (ky * 3 + kx) * cpt;
            for (int ct = 0; ct < cpt; ++ct) {
                int cc = ct * 32 + quad * 8;
                half8 a = {};
                if (ok) {
                    const short* src = (cc < C1) ? (in1 + pos * C1 + cc)
                                                 : (in2 + pos * C2 + (cc - C1));
                    a = *(const half8*)src;
                }
                size_t bi = ((size_t)(ktb + ct) * NT + nt0) * 64 + lane;
#pragma unroll
                for (int s = 0; s < 4; ++s)
                    acc[s] = __builtin_amdgcn_mfma_f32_16x16x32_f16(a, bp[bi + s * 64], acc[s], 0, 0, 0);
            }
        }
    }
#pragma unroll
    for (int s = 0; s < 4; ++s) {
        int n = (nt0 + s) * 16 + l16;
        float bs = bias[n];
#pragma unroll
        for (int r = 0; r < 4; ++r) {
            int m = wave * 16 + quad * 4 + r;
            int x = x0 + m;
            float v = fmaxf(acc[s][r] + bs, 0.f);
            outb[((size_t)y * W + x) * OC + n] = f2h(v);
        }
    }
}

__global__ __launch_bounds__(256) void convt_mfma_kernel(
    const short* __restrict__ in, int IC, const short* __restrict__ Bp,
    const float* __restrict__ bias, short* __restrict__ outb, int IH, int IW, int OC)
{
    int tid = threadIdx.x, wave = tid >> 6, lane = tid & 63;
    int quad = lane >> 4, l16 = lane & 15;
    int pz = blockIdx.z & 3, nt0 = (blockIdx.z >> 2) * 4;
    int py = pz >> 1, px = pz & 1;
    int a0 = blockIdx.y, b0 = blockIdx.x * 64;
    int cpt = IC >> 5, NT = OC >> 4, KT4 = 4 * cpt;
    const half8* bp = (const half8*)Bp;
    floatx4 acc[4] = {{0,0,0,0},{0,0,0,0},{0,0,0,0},{0,0,0,0}};
    int bm = b0 + wave * 16 + l16;
    for (int ty = 0; ty < 2; ++ty) {
        int iy = a0 + (py ? (1 - ty) : (-ty));
        bool rok = (iy >= 0) && (iy < IH);
        for (int tx = 0; tx < 2; ++tx) {
            int ix = bm + (px ? (1 - tx) : (-tx));
            bool ok = rok && (ix >= 0) && (ix < IW);
            size_t pos = (size_t)iy * IW + ix;
            int ktb = (ty * 2 + tx) * cpt;
            for (int ct = 0; ct < cpt; ++ct) {
                int cc = ct * 32 + quad * 8;
                half8 a = {};
                if (ok) a = *(const half8*)(in + pos * IC + cc);
                size_t bi = ((size_t)(pz * KT4 + ktb + ct) * NT + nt0) * 64 + lane;
#pragma unroll
                for (int s = 0; s < 4; ++s)
                    acc[s] = __builtin_amdgcn_mfma_f32_16x16x32_f16(a, bp[bi + s * 64], acc[s], 0, 0, 0);
            }
        }
    }
    int OW = IW * 2;
    int oy = 2 * a0 + py;
#pragma unroll
    for (int s = 0; s < 4; ++s) {
        int n = (nt0 + s) * 16 + l16;
        float bs = bias[n];
#pragma unroll
        for (int r = 0; r < 4; ++r) {
            int m = wave * 16 + quad * 4 + r;
            int ox = 2 * (b0 + m) + px;
            outb[((size_t)oy * OW + ox) * OC + n] = f2h(acc[s][r] + bs);
        }
    }
}

__global__ __launch_bounds__(256) void convout_mfma_kernel(
    const short* __restrict__ in, const short* __restrict__ Bp,
    const float* __restrict__ bias, float* __restrict__ out, int H, int W)
{
    int tid = threadIdx.x, wave = tid >> 6, lane = tid & 63;
    int quad = lane >> 4, l16 = lane & 15;
    int x0 = blockIdx.x * 64, y = blockIdx.y;
    const int C = 64, cpt = 2;
    const half8* bp = (const half8*)Bp;
    floatx4 acc = {0,0,0,0};
    int xm = x0 + wave * 16 + l16;
    for (int ky = 0; ky < 3; ++ky) {
        int yy = y + ky - 1;
        bool rok = (yy >= 0) && (yy < H);
        for (int kx = 0; kx < 3; ++kx) {
            int xx = xm + kx - 1;
            bool ok = rok && (xx >= 0) && (xx < W);
            size_t pos = (size_t)yy * W + xx;
            int ktb = (ky * 3 + kx) * cpt;
#pragma unroll
            for (int ct = 0; ct < cpt; ++ct) {
                int cc = ct * 32 + quad * 8;
                half8 a = {};
                if (ok) a = *(const half8*)(in + pos * C + cc);
                acc = __builtin_amdgcn_mfma_f32_16x16x32_f16(
                          a, bp[(size_t)(ktb + ct) * 64 + lane], acc, 0, 0, 0);
            }
        }
    }
    int oc = l16;
    if (oc < 3) {
        float bs = bias[oc];
#pragma unroll
        for (int r = 0; r < 4; ++r) {
            int m = wave * 16 + quad * 4 + r;
            int x = x0 + m;
            float v = acc[r] + bs;
            out[(size_t)oc * H * W + (size_t)y * W + x] = 1.f / (1.f + expf(-v));
        }
    }
}

__global__ __launch_bounds__(256) void f2h_kernel(
    const float* __restrict__ in, short* __restrict__ out, int n)
{
    int i = blockIdx.x * 256 + threadIdx.x;
    if (i < n) out[i] = f2h(in[i]);
}

// ============================================================================
extern "C" void kernel_launch(void* const* d_in, const int* in_sizes, int n_in,
                              void* d_out, int out_size, void* d_ws, size_t ws_size,
                              hipStream_t stream)
{
    const float* burst   = (const float*)d_in[0];
    const float* conv1_w = (const float*)d_in[1];  const float* conv1_b = (const float*)d_in[2];
    const float* conv2_w = (const float*)d_in[3];  const float* conv2_b = (const float*)d_in[4];
    const float* conv3_w = (const float*)d_in[5];  const float* conv3_b = (const float*)d_in[6];
    const float* ln1_g   = (const float*)d_in[7];  const float* ln1_b   = (const float*)d_in[8];
    const float* Wqk     = (const float*)d_in[9];  const float* bqk     = (const float*)d_in[10];
    const float* Wv      = (const float*)d_in[11]; const float* bvv     = (const float*)d_in[12];
    const float* Wo      = (const float*)d_in[13]; const float* bo      = (const float*)d_in[14];
    const float* rot     = (const float*)d_in[15];
    const float* ln2_g   = (const float*)d_in[16]; const float* ln2_b   = (const float*)d_in[17];
    const float* Wff1    = (const float*)d_in[18]; const float* bff1    = (const float*)d_in[19];
    const float* Wff2    = (const float*)d_in[20]; const float* bff2    = (const float*)d_in[21];
    const float* up1_w   = (const float*)d_in[22]; const float* up1_b   = (const float*)d_in[23];
    const float* dec1_w  = (const float*)d_in[24]; const float* dec1_b  = (const float*)d_in[25];
    const float* up2_w   = (const float*)d_in[26]; const float* up2_b   = (const float*)d_in[27];
    const float* dec2_w  = (const float*)d_in[28]; const float* dec2_b  = (const float*)d_in[29];
    const float* out_w   = (const float*)d_in[30]; const float* out_b   = (const float*)d_in[31];

    float* ws = (float*)d_ws;
    // persistent regions (fl offsets)
    short* e1h = (short*)(ws + 0);          // 4.19M sh
    short* e2h = (short*)(ws + 2097152);    // 2.1M sh
    float* seq = ws + 3145728;
    float* qkb = ws + 4194304;
    float* vvb = ws + 5242880;
    float* knb = ws + 6291456;
    int* buckets = (int*)(ws + 6307840);
    int* perm    = (int*)(ws + 6324224);
    short* xn0 = (short*)(ws + 6340608);    // 1.05M sh each (also oo planes)
    short* xn1 = (short*)(ws + 6864896);
    short* xn2 = (short*)(ws + 7389184);
    short* hdn0 = (short*)(ws + 7913472);   // 4.19M sh each
    short* hdn1 = (short*)(ws + 10010624);
    short* hdn2 = (short*)(ws + 12107776);
    // per-layer weight packs
    short* pqk0 = (short*)(ws + 14204928); short* pqk1 = (short*)(ws + 14237696); short* pqk2 = (short*)(ws + 14270464);
    short* pv0  = (short*)(ws + 14303232); short* pv1  = (short*)(ws + 14336000); short* pv2  = (short*)(ws + 14368768);
    short* po0  = (short*)(ws + 14401536); short* po1  = (short*)(ws + 14434304); short* po2  = (short*)(ws + 14467072);
    short* pf10 = (short*)(ws + 14499840); short* pf11 = (short*)(ws + 14630912); short* pf12 = (short*)(ws + 14761984);
    short* pf20 = (short*)(ws + 14893056); short* pf21 = (short*)(ws + 15024128); short* pf22 = (short*)(ws + 15155200);
    // decoder packs
    short* pdec1 = (short*)(ws + 15286272);
    short* pdec2 = (short*)(ws + 15433728);
    short* pout  = (short*)(ws + 15470592);
    short* pup1  = (short*)(ws + 15475200);
    short* pup2  = (short*)(ws + 15737344);   // end 15802880 fl = 60.3 MiB
    // encoder overlays
    float* e1f = ws + 7913472;                // inside hdn region
    short* p1_0 = (short*)(ws + 12107776); short* p1_1 = (short*)(ws + 12632064); short* p1_2 = (short*)(ws + 13156352);
    short* p2_0 = (short*)(ws + 13680640); short* p2_1 = (short*)(ws + 13942784); short* p2_2 = (short*)(ws + 14204928);
    short* pc2_0 = (short*)(ws + 14467072); short* pc2_1 = (short*)(ws + 14503936); short* pc2_2 = (short*)(ws + 14540800);
    short* pc3_0 = (short*)(ws + 14577664); short* pc3_1 = (short*)(ws + 14725120); short* pc3_2 = (short*)(ws + 14872576);
    short* e2_0 = (short*)(ws + 4194304); short* e2_1 = (short*)(ws + 5242880); short* e2_2 = (short*)(ws + 6291456);
    // decoder overlays (hdn region dead)
    short* seqh = (short*)(ws + 7913472);
    short* d1   = (short*)(ws + 8437760);
    short* d1c  = (short*)(ws + 9486336);
    short* d2   = (short*)(ws + 10534912);
    short* d2c  = (short*)(ws + 12632064);

    dim3 b16(16, 16);

    // ---- static packs
    pack_conv3_kernel<<<36, 256, 0, stream>>>(conv2_w, pc2_0, pc2_1, pc2_2, 64, 128, 9216);
    pack_conv3_kernel<<<144, 256, 0, stream>>>(conv3_w, pc3_0, pc3_1, pc3_2, 128, 256, 36864);
    pack_conv_kernel<<<144, 256, 0, stream>>>(dec1_w, pdec1, 256, 128, 8, 36864);
    pack_conv_kernel<<<36, 256, 0, stream>>>(dec2_w, pdec2, 128, 64, 4, 9216);
    pack_conv_kernel<<<5, 256, 0, stream>>>(out_w, pout, 64, 3, 1, 1152);
    pack_convt_kernel<<<256, 256, 0, stream>>>(up1_w, pup1, 256, 128, 65536);
    pack_convt_kernel<<<64, 256, 0, stream>>>(up2_w, pup2, 128, 64, 16384);

    // ---- encoder
    conv1_nhwc_kernel<8><<<dim3(16, 16, 8), b16, 0, stream>>>(
        burst, conv1_w, conv1_b, e1f, 256, 256, 64);
    f2h_kernel<<<16384, 256, 0, stream>>>(e1f, e1h, 4194304);
    maxpool1_bf3_kernel<<<1024, 256, 0, stream>>>(e1f, p1_0, p1_1, p1_2, 128, 256, 64);
    conv_bf3_kernel<<<dim3(2, 128, 2), 256, 0, stream>>>(
        p1_0, p1_1, p1_2, pc2_0, pc2_1, pc2_2, conv2_b,
        nullptr, e2_0, e2_1, e2_2, e2h, 128, 128, 64, 128);
    maxpool2_bf3_kernel<<<512, 256, 0, stream>>>(
        e2_0, e2_1, e2_2, p2_0, p2_1, p2_2, 64, 128, 128);
    conv_bf3_kernel<<<dim3(1, 64, 4), 256, 0, stream>>>(
        p2_0, p2_1, p2_2, pc3_0, pc3_1, pc3_2, conv3_b,
        seq, nullptr, nullptr, nullptr, nullptr, 64, 64, 128, 256);

    // ---- reformer, 4 layers (bf16x3 MFMA v2)
    for (int i = 0; i < 4; ++i) {
        pack_layer_kernel<<<352, 256, 0, stream>>>(
            Wqk + i * 65536, Wv + i * 65536, Wo + i * 65536,
            Wff1 + i * 262144, Wff2 + i * 262144,
            pqk0, pqk1, pqk2, pv0, pv1, pv2, po0, po1, po2,
            pf10, pf11, pf12, pf20, pf21, pf22);
        ln_bf3_kernel<<<1024, 256, 0, stream>>>(seq, ln1_g + i * 256, ln1_b + i * 256,
                                                xn0, xn1, xn2);
        gemm_qkv_bf3_kernel<<<dim3(16, 64), 256, 0, stream>>>(
            xn0, xn1, xn2, pqk0, pqk1, pqk2, bqk + i * 256, qkb,
            pv0, pv1, pv2, bvv + i * 256, vvb, 256);
        bucketn_kernel<<<64, 256, 0, stream>>>(qkb, rot + i * 8192, buckets, knb);
        lsh_sort_kernel<<<4, 256, 0, stream>>>(buckets, perm);
        attn_kernel<<<dim3(64, 4), 256, 0, stream>>>(qkb, vvb, knb, perm, xn0, xn1, xn2);
        gemm_bf3_kernel<<<dim3(8, 64), 256, 0, stream>>>(
            xn0, xn1, xn2, po0, po1, po2, bo + i * 256, seq,
            nullptr, nullptr, nullptr, 256, 256, 0, 1);
        ln_bf3_kernel<<<1024, 256, 0, stream>>>(seq, ln2_g + i * 256, ln2_b + i * 256,
                                                xn0, xn1, xn2);
        gemm_bf3_kernel<<<dim3(32, 64), 256, 0, stream>>>(
            xn0, xn1, xn2, pf10, pf11, pf12, bff1 + i * 1024, nullptr,
            hdn0, hdn1, hdn2, 1024, 256, 1, 0);
        gemm_bf3_kernel<<<dim3(8, 64), 256, 0, stream>>>(
            hdn0, hdn1, hdn2, pf20, pf21, pf22, bff2 + i * 256, seq,
            nullptr, nullptr, nullptr, 256, 1024, 0, 1);
    }

    // ---- decoder (plain fp16 MFMA)
    f2h_kernel<<<4096, 256, 0, stream>>>(seq, seqh, 1048576);
    convt_mfma_kernel<<<dim3(1, 64, 8), 256, 0, stream>>>(
        seqh, 256, pup1, up1_b, d1, 64, 64, 128);
    conv_mfma_kernel<<<dim3(2, 128, 2), 256, 0, stream>>>(
        d1, 128, e2h, 128, pdec1, dec1_b, d1c, 128, 128, 128);
    convt_mfma_kernel<<<dim3(2, 128, 4), 256, 0, stream>>>(
        d1c, 128, pup2, up2_b, d2, 128, 128, 64);
    conv_mfma_kernel<<<dim3(4, 256, 1), 256, 0, stream>>>(
        d2, 64, e1h, 64, pdec2, dec2_b, d2c, 256, 256, 64);
    convout_mfma_kernel<<<dim3(4, 256), 256, 0, stream>>>(
        d2c, pout, out_b, (float*)d_out, 256, 256);
}

// Round 11
// 1321.124 us; speedup vs baseline: 1.0438x; 1.0438x over previous
//
#include <hip/hip_runtime.h>
#include <hip/hip_bf16.h>
#include <math.h>

using short8  = __attribute__((ext_vector_type(8))) short;
using half8   = __attribute__((ext_vector_type(8))) _Float16;
using floatx4 = __attribute__((ext_vector_type(4))) float;

static __device__ __forceinline__ float gelu_f(float x) {
    float x3 = x * x * x;
    return 0.5f * x * (1.f + tanhf(0.7978845608028654f * (x + 0.044715f * x3)));
}
static __device__ __forceinline__ short f2h(float f) {
    _Float16 h = (_Float16)f;
    return __builtin_bit_cast(short, h);
}
static __device__ __forceinline__ short f2bf(float f) {
    unsigned u = __float_as_uint(f);
    u += 0x7fffu + ((u >> 16) & 1u);   // RNE
    return (short)(u >> 16);
}
static __device__ __forceinline__ float bf2f(short s) {
    return __uint_as_float(((unsigned)(unsigned short)s) << 16);
}
struct bf3s { short a, b, c; };
static __device__ __forceinline__ bf3s split3(float v) {
    short c0 = f2bf(v); float r = v - bf2f(c0);
    short c1 = f2bf(r); r -= bf2f(c1);
    short c2 = f2bf(r);
    bf3s s; s.a = c0; s.b = c1; s.c = c2; return s;
}

// ============================================================================
// conv1 (C=3): fp32 direct, NHWC fp32 out + fp16 dual write
// ============================================================================
template <int OCB>
__global__ __launch_bounds__(256) void conv1_nhwc_kernel(
    const float* __restrict__ in1, const float* __restrict__ w,
    const float* __restrict__ bias, float* __restrict__ out,
    short* __restrict__ outh, int H, int W, int OC)
{
    int tx = threadIdx.x, ty = threadIdx.y;
    int x = blockIdx.x * 16 + tx, y = blockIdx.y * 16 + ty;
    int oc0 = blockIdx.z * OCB;
    const int C = 3;
    float acc[OCB];
#pragma unroll
    for (int o = 0; o < OCB; ++o) acc[o] = 0.f;
    for (int ic = 0; ic < C; ++ic) {
        const float* src = in1 + (size_t)ic * H * W;
        float v[9];
#pragma unroll
        for (int ky = 0; ky < 3; ++ky) {
            int iy = y + ky - 1;
            bool okY = (iy >= 0) && (iy < H);
#pragma unroll
            for (int kx = 0; kx < 3; ++kx) {
                int ix = x + kx - 1;
                bool ok = okY && (ix >= 0) && (ix < W);
                v[ky * 3 + kx] = ok ? src[(size_t)iy * W + ix] : 0.f;
            }
        }
        const float* wp = w + ((size_t)oc0 * C + ic) * 9;
#pragma unroll
        for (int o = 0; o < OCB; ++o) {
            const float* wo = wp + (size_t)o * C * 9;
            acc[o] += v[0]*wo[0] + v[1]*wo[1] + v[2]*wo[2]
                    + v[3]*wo[3] + v[4]*wo[4] + v[5]*wo[5]
                    + v[6]*wo[6] + v[7]*wo[7] + v[8]*wo[8];
        }
    }
    size_t ob = ((size_t)y * W + x) * OC + oc0;
#pragma unroll
    for (int o = 0; o < OCB; ++o) {
        float r = fmaxf(acc[o] + bias[oc0 + o], 0.f);
        out[ob + o] = r;
        outh[ob + o] = f2h(r);
    }
}

// ============================================================================
// maxpools with bf16x3 split outputs (NHWC)
// ============================================================================
__global__ __launch_bounds__(256) void maxpool1_bf3_kernel(
    const float* __restrict__ in, short* __restrict__ o0, short* __restrict__ o1,
    short* __restrict__ o2, int OW, int IW, int C)
{
    int idx = blockIdx.x * 256 + threadIdx.x;
    int g = idx % (C >> 2); int p = idx / (C >> 2);
    int x = p % OW; int y = p / OW;
    size_t base = ((size_t)(2 * y) * IW + 2 * x) * C + g * 4;
    float4 a = *(const float4*)(in + base);
    float4 b = *(const float4*)(in + base + C);
    float4 c = *(const float4*)(in + base + (size_t)IW * C);
    float4 d = *(const float4*)(in + base + (size_t)IW * C + C);
    float v[4];
    v[0] = fmaxf(fmaxf(a.x, b.x), fmaxf(c.x, d.x));
    v[1] = fmaxf(fmaxf(a.y, b.y), fmaxf(c.y, d.y));
    v[2] = fmaxf(fmaxf(a.z, b.z), fmaxf(c.z, d.z));
    v[3] = fmaxf(fmaxf(a.w, b.w), fmaxf(c.w, d.w));
    size_t o = (size_t)p * C + g * 4;
#pragma unroll
    for (int j = 0; j < 4; ++j) {
        bf3s s = split3(v[j]);
        o0[o + j] = s.a; o1[o + j] = s.b; o2[o + j] = s.c;
    }
}

__global__ __launch_bounds__(256) void maxpool2_bf3_kernel(
    const short* __restrict__ i0, const short* __restrict__ i1,
    const short* __restrict__ i2, short* __restrict__ o0, short* __restrict__ o1,
    short* __restrict__ o2, int OW, int IW, int C)
{
    int idx = blockIdx.x * 256 + threadIdx.x;
    int g = idx % (C >> 2); int p = idx / (C >> 2);
    int x = p % OW; int y = p / OW;
    float v[4] = {-1e30f, -1e30f, -1e30f, -1e30f};
#pragma unroll
    for (int dy = 0; dy < 2; ++dy)
#pragma unroll
        for (int dx = 0; dx < 2; ++dx) {
            size_t base = ((size_t)(2 * y + dy) * IW + 2 * x + dx) * C + g * 4;
#pragma unroll
            for (int j = 0; j < 4; ++j) {
                float u = bf2f(i0[base + j]) + bf2f(i1[base + j]) + bf2f(i2[base + j]);
                v[j] = fmaxf(v[j], u);
            }
        }
    size_t o = (size_t)p * C + g * 4;
#pragma unroll
    for (int j = 0; j < 4; ++j) {
        bf3s s = split3(v[j]);
        o0[o + j] = s.a; o1[o + j] = s.b; o2[o + j] = s.c;
    }
}

// ============================================================================
// pack conv weights -> 3 bf16 planes, k = (ky*3+kx)*C + c
// ============================================================================
__global__ void pack_conv3_kernel(const float* __restrict__ w,
                                  short* __restrict__ B0, short* __restrict__ B1,
                                  short* __restrict__ B2, int C, int OC, int total)
{
    int t = blockIdx.x * 256 + threadIdx.x;
    if (t >= total) return;
    int lane = t & 63, fi = t >> 6;
    int NT = OC >> 4;
    int nt = fi % NT, kt = fi / NT;
    int cpt = C >> 5;
    int tap = kt / cpt, ct = kt % cpt;
    int c = ct * 32 + (lane >> 4) * 8;
    int oc = nt * 16 + (lane & 15);
    short8 v0, v1, v2;
#pragma unroll
    for (int j = 0; j < 8; ++j) {
        bf3s s = split3(w[((size_t)oc * C + c + j) * 9 + tap]);
        v0[j] = s.a; v1[j] = s.b; v2[j] = s.c;
    }
    ((short8*)B0)[t] = v0; ((short8*)B1)[t] = v1; ((short8*)B2)[t] = v2;
}

// ============================================================================
// bf16x3 implicit-GEMM 3x3 conv (conv2/conv3) — R9-proven
// ============================================================================
__global__ __launch_bounds__(256) void conv_bf3_kernel(
    const short* __restrict__ ia0, const short* __restrict__ ia1,
    const short* __restrict__ ia2,
    const short* __restrict__ B0, const short* __restrict__ B1,
    const short* __restrict__ B2, const float* __restrict__ bias,
    float* __restrict__ outf, short* __restrict__ o0, short* __restrict__ o1,
    short* __restrict__ o2, short* __restrict__ oh,
    int H, int W, int C, int OC)
{
    int tid = threadIdx.x, wave = tid >> 6, lane = tid & 63;
    int quad = lane >> 4, l16 = lane & 15;
    int x0 = blockIdx.x * 64, y = blockIdx.y, nt0 = blockIdx.z * 4;
    int cpt = C >> 5, NT = OC >> 4;
    const short8* b0p = (const short8*)B0;
    const short8* b1p = (const short8*)B1;
    const short8* b2p = (const short8*)B2;
    floatx4 aM[4] = {{0,0,0,0},{0,0,0,0},{0,0,0,0},{0,0,0,0}};
    floatx4 aC[4] = {{0,0,0,0},{0,0,0,0},{0,0,0,0},{0,0,0,0}};
    int xm = x0 + wave * 16 + l16;
    for (int ky = 0; ky < 3; ++ky) {
        int yy = y + ky - 1;
        bool rok = (yy >= 0) && (yy < H);
        for (int kx = 0; kx < 3; ++kx) {
            int xx = xm + kx - 1;
            bool ok = rok && (xx >= 0) && (xx < W);
            size_t pos = (size_t)yy * W + xx;
            int ktb = (ky * 3 + kx) * cpt;
            for (int ct = 0; ct < cpt; ++ct) {
                int cc = ct * 32 + quad * 8;
                short8 A0 = {0,0,0,0,0,0,0,0}, A1 = A0, A2 = A0;
                if (ok) {
                    A0 = *(const short8*)(ia0 + pos * C + cc);
                    A1 = *(const short8*)(ia1 + pos * C + cc);
                    A2 = *(const short8*)(ia2 + pos * C + cc);
                }
                size_t bi = ((size_t)(ktb + ct) * NT + nt0) * 64 + lane;
#pragma unroll
                for (int s = 0; s < 4; ++s) {
                    short8 w0 = b0p[bi + s * 64];
                    short8 w1 = b1p[bi + s * 64];
                    short8 w2 = b2p[bi + s * 64];
                    aM[s] = __builtin_amdgcn_mfma_f32_16x16x32_bf16(A0, w0, aM[s], 0, 0, 0);
                    aC[s] = __builtin_amdgcn_mfma_f32_16x16x32_bf16(A0, w1, aC[s], 0, 0, 0);
                    aC[s] = __builtin_amdgcn_mfma_f32_16x16x32_bf16(A1, w0, aC[s], 0, 0, 0);
                    aC[s] = __builtin_amdgcn_mfma_f32_16x16x32_bf16(A0, w2, aC[s], 0, 0, 0);
                    aC[s] = __builtin_amdgcn_mfma_f32_16x16x32_bf16(A1, w1, aC[s], 0, 0, 0);
                    aC[s] = __builtin_amdgcn_mfma_f32_16x16x32_bf16(A2, w0, aC[s], 0, 0, 0);
                }
            }
        }
    }
#pragma unroll
    for (int s = 0; s < 4; ++s) {
        int n = (nt0 + s) * 16 + l16;
        float bs = bias[n];
#pragma unroll
        for (int r = 0; r < 4; ++r) {
            int m = wave * 16 + quad * 4 + r;
            int x = x0 + m;
            float v = fmaxf(aM[s][r] + aC[s][r] + bs, 0.f);
            size_t o = ((size_t)y * W + x) * OC + n;
            if (outf) outf[o] = v;
            else {
                bf3s sp = split3(v);
                o0[o] = sp.a; o1[o] = sp.b; o2[o] = sp.c;
                oh[o] = f2h(v);
            }
        }
    }
}

// ============================================================================
// LayerNorm: fp32 math, bf16x3 plane outputs
// ============================================================================
__global__ __launch_bounds__(256) void ln_bf3_kernel(
    const float* __restrict__ x, const float* __restrict__ g,
    const float* __restrict__ b, short* __restrict__ y0,
    short* __restrict__ y1, short* __restrict__ y2)
{
    int wave = threadIdx.x >> 6, lane = threadIdx.x & 63;
    int n = blockIdx.x * 4 + wave;
    const float* xr = x + (size_t)n * 256;
    float4 v = *(const float4*)(xr + lane * 4);
    float s = v.x + v.y + v.z + v.w;
#pragma unroll
    for (int m = 1; m < 64; m <<= 1) s += __shfl_xor(s, m);
    float mean = s * (1.f / 256.f);
    float cx = v.x - mean, cy = v.y - mean, cz = v.z - mean, cw = v.w - mean;
    float q = cx * cx + cy * cy + cz * cz + cw * cw;
#pragma unroll
    for (int m = 1; m < 64; m <<= 1) q += __shfl_xor(q, m);
    float rstd = rsqrtf(q * (1.f / 256.f) + 1e-5f);
    float4 gv = *(const float4*)(g + lane * 4);
    float4 bv = *(const float4*)(b + lane * 4);
    float o[4];
    o[0] = cx * rstd * gv.x + bv.x;
    o[1] = cy * rstd * gv.y + bv.y;
    o[2] = cz * rstd * gv.z + bv.z;
    o[3] = cw * rstd * gv.w + bv.w;
    size_t ob = (size_t)n * 256 + lane * 4;
#pragma unroll
    for (int j = 0; j < 4; ++j) {
        bf3s sp = split3(o[j]);
        y0[ob + j] = sp.a; y1[ob + j] = sp.b; y2[ob + j] = sp.c;
    }
}

// ============================================================================
// fused bucket + knorm (fp32, bucket-critical)
// ============================================================================
__global__ __launch_bounds__(256) void bucketn_kernel(
    const float* __restrict__ qk, const float* __restrict__ rot,
    int* __restrict__ buckets, float* __restrict__ knrm)
{
    int t = blockIdx.x * 256 + threadIdx.x;
    int h = t >> 12, n = t & 4095;
    const float* q = qk + (size_t)n * 256 + h * 64;
    const float* R = rot + (size_t)h * 2048;
    float acc[32];
#pragma unroll
    for (int r = 0; r < 32; ++r) acc[r] = 0.f;
    float s2 = 0.f;
    for (int d = 0; d < 64; ++d) {
        float qd = q[d];
        s2 += qd * qd;
        const float* Rd = R + d * 32;
#pragma unroll
        for (int r = 0; r < 32; ++r) acc[r] += qd * Rd[r];
    }
    knrm[t] = 1.f / (sqrtf(s2) + 1e-6f);
    float bvv = acc[0]; int best = 0;
#pragma unroll
    for (int j = 1; j < 64; ++j) {
        float val = (j < 32) ? acc[j] : -acc[j - 32];
        if (val > bvv) { bvv = val; best = j; }
    }
    buckets[t] = best;
}

__global__ __launch_bounds__(256) void lsh_sort_kernel(
    const int* __restrict__ buckets, int* __restrict__ perm)
{
    int h = blockIdx.x;
    const int* bk = buckets + h * 4096;
    __shared__ unsigned long long mask[64][64];
    __shared__ int counts[64];
    __shared__ int offsets[64];
    __shared__ int wpre[64][64];
    int tid = threadIdx.x, wave = tid >> 6, lane = tid & 63;
    for (int w = wave * 16; w < wave * 16 + 16; ++w) {
        int bl = bk[w * 64 + lane];
        for (int b = 0; b < 64; ++b) {
            unsigned long long m = __ballot(bl == b);
            if (lane == b) mask[b][w] = m;
        }
    }
    __syncthreads();
    if (tid < 64) {
        int c = 0;
        for (int w = 0; w < 64; ++w) c += __popcll(mask[tid][w]);
        counts[tid] = c;
    }
    __syncthreads();
    if (tid == 0) {
        int a = 0;
        for (int b = 0; b < 64; ++b) { offsets[b] = a; a += counts[b]; }
    }
    __syncthreads();
    for (int b = wave * 16; b < wave * 16 + 16; ++b) {
        int c = __popcll(mask[b][lane]);
        int incl = c;
#pragma unroll
        for (int off = 1; off < 64; off <<= 1) {
            int nb = __shfl_up(incl, off);
            if (lane >= off) incl += nb;
        }
        wpre[b][lane] = incl - c + offsets[b];
    }
    __syncthreads();
    for (int i = tid; i < 4096; i += 256) {
        int b = bk[i]; int w = i >> 6; int l = i & 63;
        unsigned long long below = mask[b][w] & ((1ull << l) - 1ull);
        int pos = wpre[b][w] + __popcll(below);
        perm[h * 4096 + pos] = i;
    }
}

// ============================================================================
// attention v2: 32 rows/block, 8 threads/row, parallel softmax, fused scale.
// grid (64 chunks, 4 heads, 2 row-halves). fp32 math, bf16x3 plane outputs.
// ============================================================================
__global__ __launch_bounds__(256) void attn_kernel(
    const float* __restrict__ qk, const float* __restrict__ vv,
    const float* __restrict__ knrm, const int* __restrict__ perm,
    short* __restrict__ o0, short* __restrict__ o1, short* __restrict__ o2)
{
    __shared__ float ks[128 * 64];      // keys, then values
    __shared__ float dotsT[128 * 32];   // [j][rr] scores (then exp weights)
    __shared__ float pmax[8][32];
    __shared__ float psum[8][32];
    int c = blockIdx.x, h = blockIdx.y, rh = blockIdx.z;
    int tid = threadIdx.x;
    const int* pm = perm + h * 4096;
    int cm = (c + 63) & 63;
    // stage normalized keys: 128 rows, 2 threads/row
    {
        int jr = tid >> 1, hf = tid & 1;
        int sk = (jr < 64) ? (c * 64 + jr) : (cm * 64 + (jr - 64));
        int nk = pm[sk];
        float sc = knrm[h * 4096 + nk];
        const float* src = qk + (size_t)nk * 256 + h * 64 + hf * 32;
        float* dst = ks + jr * 64 + hf * 32;
#pragma unroll
        for (int d = 0; d < 32; d += 4) {
            float4 v = *(const float4*)(src + d);
            v.x *= sc; v.y *= sc; v.z *= sc; v.w *= sc;
            *(float4*)(dst + d) = v;
        }
    }
    __syncthreads();
    int rr = tid & 31, jq = tid >> 5;   // row-in-block, j-group
    int r = rh * 32 + rr;
    int nq = pm[c * 64 + r];
    float mx = -1e30f;
    {
        float qreg[64];
        const float* src = qk + (size_t)nq * 256 + h * 64;
#pragma unroll
        for (int d = 0; d < 64; d += 4) {
            float4 v = *(const float4*)(src + d);
            qreg[d] = v.x; qreg[d + 1] = v.y; qreg[d + 2] = v.z; qreg[d + 3] = v.w;
        }
        for (int jj = 0; jj < 16; ++jj) {
            int j = jq * 16 + jj;
            const float* kr = ks + j * 64;
            float dot = 0.f;
#pragma unroll
            for (int d = 0; d < 64; d += 4) {
                float4 kv = *(const float4*)(kr + d);
                dot += qreg[d] * kv.x + qreg[d + 1] * kv.y
                     + qreg[d + 2] * kv.z + qreg[d + 3] * kv.w;
            }
            int sk = (j < 64) ? (c * 64 + j) : (cm * 64 + (j - 64));
            int nk = pm[sk];
            dot = (nk == nq) ? -1e5f : dot * 0.125f;
            dotsT[j * 32 + rr] = dot;
            mx = fmaxf(mx, dot);
        }
    }
    pmax[jq][rr] = mx;
    __syncthreads();   // dots complete (ks free), pmax ready
    float gmax = pmax[0][rr];
#pragma unroll
    for (int g = 1; g < 8; ++g) gmax = fmaxf(gmax, pmax[g][rr]);
    float ss = 0.f;
    for (int jj = 0; jj < 16; ++jj) {
        int j = jq * 16 + jj;
        float e = expf(dotsT[j * 32 + rr] - gmax);
        dotsT[j * 32 + rr] = e;
        ss += e;
    }
    psum[jq][rr] = ss;
    // stage values over ks (safe: all ks reads done at last barrier)
    {
        int jr = tid >> 1, hf = tid & 1;
        int sk = (jr < 64) ? (c * 64 + jr) : (cm * 64 + (jr - 64));
        int nk = pm[sk];
        const float* src = vv + (size_t)nk * 256 + h * 64 + hf * 32;
        float* dst = ks + jr * 64 + hf * 32;
#pragma unroll
        for (int d = 0; d < 32; d += 4)
            *(float4*)(dst + d) = *(const float4*)(src + d);
    }
    __syncthreads();
    float tot = psum[0][rr];
#pragma unroll
    for (int g = 1; g < 8; ++g) tot += psum[g][rr];
    float inv = 1.f / tot;
    // PV: row r, d-slice jq*8..+8, unnormalized weights, scale at end
    float acc[8] = {0.f, 0.f, 0.f, 0.f, 0.f, 0.f, 0.f, 0.f};
    for (int j = 0; j < 128; ++j) {
        float a = dotsT[j * 32 + rr];
        const float* vr = ks + j * 64 + jq * 8;
        float4 v0 = *(const float4*)(vr);
        float4 v1 = *(const float4*)(vr + 4);
        acc[0] += a * v0.x; acc[1] += a * v0.y; acc[2] += a * v0.z; acc[3] += a * v0.w;
        acc[4] += a * v1.x; acc[5] += a * v1.y; acc[6] += a * v1.z; acc[7] += a * v1.w;
    }
    size_t ob = (size_t)nq * 256 + h * 64 + jq * 8;
#pragma unroll
    for (int d = 0; d < 8; ++d) {
        bf3s sp = split3(acc[d] * inv);
        o0[ob + d] = sp.a; o1[ob + d] = sp.b; o2[ob + d] = sp.c;
    }
}

// ============================================================================
// fused per-layer weight pack: 5 matrices -> 15 bf16 fragment planes
// ============================================================================
static __device__ __forceinline__ void pack_one(
    const float* __restrict__ W, short* __restrict__ B0, short* __restrict__ B1,
    short* __restrict__ B2, int N, int t)
{
    int lane = t & 63, fi = t >> 6;
    int NT = N >> 4;
    int nt = fi % NT, kt = fi / NT;
    int n = nt * 16 + (lane & 15);
    int k0 = kt * 32 + (lane >> 4) * 8;
    short8 v0, v1, v2;
#pragma unroll
    for (int j = 0; j < 8; ++j) {
        bf3s s = split3(W[(size_t)(k0 + j) * N + n]);
        v0[j] = s.a; v1[j] = s.b; v2[j] = s.c;
    }
    ((short8*)B0)[t] = v0; ((short8*)B1)[t] = v1; ((short8*)B2)[t] = v2;
}

__global__ void pack_layer_kernel(
    const float* __restrict__ Wqk, const float* __restrict__ Wv,
    const float* __restrict__ Wo, const float* __restrict__ Wff1,
    const float* __restrict__ Wff2,
    short* q0, short* q1, short* q2, short* v0, short* v1, short* v2,
    short* o0, short* o1, short* o2, short* f10, short* f11, short* f12,
    short* f20, short* f21, short* f22)
{
    int t = blockIdx.x * 256 + threadIdx.x;
    if (t < 8192)       pack_one(Wqk, q0, q1, q2, 256, t);
    else if (t < 16384) pack_one(Wv, v0, v1, v2, 256, t - 8192);
    else if (t < 24576) pack_one(Wo, o0, o1, o2, 256, t - 16384);
    else if (t < 57344) pack_one(Wff1, f10, f11, f12, 1024, t - 24576);
    else if (t < 90112) pack_one(Wff2, f20, f21, f22, 256, t - 57344);
}

// ============================================================================
// bf16x3 GEMM v2 (R10): per-wave N=32, register prefetch, dual correction acc.
// out fp32 (+resid, optional fp16 dual) or 3 bf16 planes.
// ============================================================================
static __device__ __forceinline__ void gemm_bf3_core(
    const short* __restrict__ A0, const short* __restrict__ A1,
    const short* __restrict__ A2,
    const short* __restrict__ B0, const short* __restrict__ B1,
    const short* __restrict__ B2, const float* __restrict__ bias,
    float* __restrict__ Cf, short* __restrict__ D0, short* __restrict__ D1,
    short* __restrict__ D2, short* __restrict__ Dh,
    int N, int K, int act, int resid, int bx, int by)
{
    int tid = threadIdx.x, wave = tid >> 6, lane = tid & 63;
    int quad = lane >> 4, l16 = lane & 15;
    int m0 = by * 64 + wave * 16;
    int NT = N >> 4, nt0 = bx * 2;
    size_t arow = (size_t)(m0 + l16) * K + quad * 8;
    const short8* b0p = (const short8*)B0;
    const short8* b1p = (const short8*)B1;
    const short8* b2p = (const short8*)B2;
    floatx4 aM0 = {0,0,0,0}, aM1 = {0,0,0,0};
    floatx4 aC10 = {0,0,0,0}, aC11 = {0,0,0,0};
    floatx4 aC20 = {0,0,0,0}, aC21 = {0,0,0,0};
    int KT = K >> 5;
    size_t bi0 = (size_t)nt0 * 64 + lane;
    short8 a0 = *(const short8*)(A0 + arow);
    short8 a1 = *(const short8*)(A1 + arow);
    short8 a2 = *(const short8*)(A2 + arow);
    short8 w00 = b0p[bi0], w01 = b1p[bi0], w02 = b2p[bi0];
    short8 w10 = b0p[bi0 + 64], w11 = b1p[bi0 + 64], w12 = b2p[bi0 + 64];
    for (int kt = 0; kt < KT; ++kt) {
        short8 na0 = {}, na1 = {}, na2 = {};
        short8 nw00 = {}, nw01 = {}, nw02 = {}, nw10 = {}, nw11 = {}, nw12 = {};
        if (kt + 1 < KT) {
            size_t ar = arow + (size_t)(kt + 1) * 32;
            na0 = *(const short8*)(A0 + ar);
            na1 = *(const short8*)(A1 + ar);
            na2 = *(const short8*)(A2 + ar);
            size_t nbi = ((size_t)(kt + 1) * NT + nt0) * 64 + lane;
            nw00 = b0p[nbi]; nw01 = b1p[nbi]; nw02 = b2p[nbi];
            nw10 = b0p[nbi + 64]; nw11 = b1p[nbi + 64]; nw12 = b2p[nbi + 64];
        }
        aM0  = __builtin_amdgcn_mfma_f32_16x16x32_bf16(a0, w00, aM0, 0, 0, 0);
        aM1  = __builtin_amdgcn_mfma_f32_16x16x32_bf16(a0, w10, aM1, 0, 0, 0);
        aC10 = __builtin_amdgcn_mfma_f32_16x16x32_bf16(a0, w01, aC10, 0, 0, 0);
        aC11 = __builtin_amdgcn_mfma_f32_16x16x32_bf16(a0, w11, aC11, 0, 0, 0);
        aC20 = __builtin_amdgcn_mfma_f32_16x16x32_bf16(a1, w00, aC20, 0, 0, 0);
        aC21 = __builtin_amdgcn_mfma_f32_16x16x32_bf16(a1, w10, aC21, 0, 0, 0);
        aC10 = __builtin_amdgcn_mfma_f32_16x16x32_bf16(a0, w02, aC10, 0, 0, 0);
        aC11 = __builtin_amdgcn_mfma_f32_16x16x32_bf16(a0, w12, aC11, 0, 0, 0);
        aC20 = __builtin_amdgcn_mfma_f32_16x16x32_bf16(a1, w01, aC20, 0, 0, 0);
        aC21 = __builtin_amdgcn_mfma_f32_16x16x32_bf16(a1, w11, aC21, 0, 0, 0);
        aC10 = __builtin_amdgcn_mfma_f32_16x16x32_bf16(a2, w00, aC10, 0, 0, 0);
        aC11 = __builtin_amdgcn_mfma_f32_16x16x32_bf16(a2, w10, aC11, 0, 0, 0);
        a0 = na0; a1 = na1; a2 = na2;
        w00 = nw00; w01 = nw01; w02 = nw02;
        w10 = nw10; w11 = nw11; w12 = nw12;
    }
    floatx4 aM[2] = {aM0, aM1};
    floatx4 c1[2] = {aC10, aC11};
    floatx4 c2[2] = {aC20, aC21};
#pragma unroll
    for (int s = 0; s < 2; ++s) {
        int n = (nt0 + s) * 16 + l16;
        float bs = bias[n];
#pragma unroll
        for (int r = 0; r < 4; ++r) {
            int m = m0 + quad * 4 + r;
            float v = aM[s][r] + (c1[s][r] + c2[s][r]) + bs;
            if (act == 1) v = gelu_f(v);
            size_t o = (size_t)m * N + n;
            if (D0) {
                bf3s sp = split3(v);
                D0[o] = sp.a; D1[o] = sp.b; D2[o] = sp.c;
            } else {
                if (resid) v += Cf[o];
                Cf[o] = v;
                if (Dh) Dh[o] = f2h(v);
            }
        }
    }
}

__global__ __launch_bounds__(256) void gemm_bf3_kernel(
    const short* A0, const short* A1, const short* A2,
    const short* B0, const short* B1, const short* B2,
    const float* bias, float* Cf, short* D0, short* D1, short* D2, short* Dh,
    int N, int K, int act, int resid)
{
    gemm_bf3_core(A0, A1, A2, B0, B1, B2, bias, Cf, D0, D1, D2, Dh,
                  N, K, act, resid, blockIdx.x, blockIdx.y);
}

// fused QK|V (N=256 each): blocks x<8 -> QK, else V
__global__ __launch_bounds__(256) void gemm_qkv_bf3_kernel(
    const short* A0, const short* A1, const short* A2,
    const short* Q0, const short* Q1, const short* Q2,
    const float* qb, float* Cq,
    const short* V0, const short* V1, const short* V2,
    const float* vb, float* Cv, int K)
{
    int side = blockIdx.x >> 3;
    gemm_bf3_core(A0, A1, A2, side ? V0 : Q0, side ? V1 : Q1, side ? V2 : Q2,
                  side ? vb : qb, side ? Cv : Cq, nullptr, nullptr, nullptr,
                  nullptr, 256, K, 0, 0, blockIdx.x & 7, blockIdx.y);
}

// ============================================================================
// plain fp16 MFMA decoder kernels (R8-proven)
// ============================================================================
__global__ void pack_conv_kernel(const float* __restrict__ w, short* __restrict__ Bp,
                                 int C, int OC, int NT, int total)
{
    int t = blockIdx.x * 256 + threadIdx.x;
    if (t >= total) return;
    int lane = t & 63, fi = t >> 6;
    int nt = fi % NT, kt = fi / NT;
    int cpt = C >> 5;
    int tap = kt / cpt, ct = kt % cpt;
    int c = ct * 32 + (lane >> 4) * 8;
    int oc = nt * 16 + (lane & 15);
    short8 v;
#pragma unroll
    for (int j = 0; j < 8; ++j) {
        float f = (oc < OC) ? w[((size_t)oc * C + c + j) * 9 + tap] : 0.f;
        v[j] = f2h(f);
    }
    ((short8*)Bp)[t] = v;
}

__global__ void pack_convt_kernel(const float* __restrict__ w, short* __restrict__ Bp,
                                  int IC, int OC, int total)
{
    int t = blockIdx.x * 256 + threadIdx.x;
    if (t >= total) return;
    int lane = t & 63, fi = t >> 6;
    int NT = OC >> 4, cpt = IC >> 5, KT4 = 4 * cpt;
    int nt = fi % NT, r = fi / NT;
    int kt = r % KT4, pz = r / KT4;
    int py = pz >> 1, px = pz & 1;
    int t4 = kt / cpt, ct = kt % cpt;
    int ty = t4 >> 1, tx = t4 & 1;
    int ky = py ? (2 * ty) : (1 + 2 * ty);
    int kx = px ? (2 * tx) : (1 + 2 * tx);
    int ic = ct * 32 + (lane >> 4) * 8;
    int oc = nt * 16 + (lane & 15);
    short8 v;
#pragma unroll
    for (int j = 0; j < 8; ++j)
        v[j] = f2h(w[(((size_t)(ic + j) * OC + oc) * 4 + ky) * 4 + kx]);
    ((short8*)Bp)[t] = v;
}

__global__ __launch_bounds__(256) void conv_mfma_kernel(
    const short* __restrict__ in1, int C1, const short* __restrict__ in2, int C2,
    const short* __restrict__ Bp, const float* __restrict__ bias,
    short* __restrict__ outb, int H, int W, int OC)
{
    int tid = threadIdx.x, wave = tid >> 6, lane = tid & 63;
    int quad = lane >> 4, l16 = lane & 15;
    int x0 = blockIdx.x * 64, y = blockIdx.y, nt0 = blockIdx.z * 4;
    int C = C1 + C2, cpt = C >> 5, NT = OC >> 4;
    const half8* bp = (const half8*)Bp;
    floatx4 acc[4] = {{0,0,0,0},{0,0,0,0},{0,0,0,0},{0,0,0,0}};
    int xm = x0 + wave * 16 + l16;
    for (int ky = 0; ky < 3; ++ky) {
        int yy = y + ky - 1;
        bool rok = (yy >= 0) && (yy < H);
        for (int kx = 0; kx < 3; ++kx) {
            int xx = xm + kx - 1;
            bool ok = rok && (xx >= 0) && (xx < W);
            size_t pos = (size_t)yy * W + xx;
            int ktb = (ky * 3 + kx) * cpt;
            for (int ct = 0; ct < cpt; ++ct) {
                int cc = ct * 32 + quad * 8;
                half8 a = {};
                if (ok) {
                    const short* src = (cc < C1) ? (in1 + pos * C1 + cc)
                                                 : (in2 + pos * C2 + (cc - C1));
                    a = *(const half8*)src;
                }
                size_t bi = ((size_t)(ktb + ct) * NT + nt0) * 64 + lane;
#pragma unroll
                for (int s = 0; s < 4; ++s)
                    acc[s] = __builtin_amdgcn_mfma_f32_16x16x32_f16(a, bp[bi + s * 64], acc[s], 0, 0, 0);
            }
        }
    }
#pragma unroll
    for (int s = 0; s < 4; ++s) {
        int n = (nt0 + s) * 16 + l16;
        float bs = bias[n];
#pragma unroll
        for (int r = 0; r < 4; ++r) {
            int m = wave * 16 + quad * 4 + r;
            int x = x0 + m;
            float v = fmaxf(acc[s][r] + bs, 0.f);
            outb[((size_t)y * W + x) * OC + n] = f2h(v);
        }
    }
}

__global__ __launch_bounds__(256) void convt_mfma_kernel(
    const short* __restrict__ in, int IC, const short* __restrict__ Bp,
    const float* __restrict__ bias, short* __restrict__ outb, int IH, int IW, int OC)
{
    int tid = threadIdx.x, wave = tid >> 6, lane = tid & 63;
    int quad = lane >> 4, l16 = lane & 15;
    int pz = blockIdx.z & 3, nt0 = (blockIdx.z >> 2) * 4;
    int py = pz >> 1, px = pz & 1;
    int a0 = blockIdx.y, b0 = blockIdx.x * 64;
    int cpt = IC >> 5, NT = OC >> 4, KT4 = 4 * cpt;
    const half8* bp = (const half8*)Bp;
    floatx4 acc[4] = {{0,0,0,0},{0,0,0,0},{0,0,0,0},{0,0,0,0}};
    int bm = b0 + wave * 16 + l16;
    for (int ty = 0; ty < 2; ++ty) {
        int iy = a0 + (py ? (1 - ty) : (-ty));
        bool rok = (iy >= 0) && (iy < IH);
        for (int tx = 0; tx < 2; ++tx) {
            int ix = bm + (px ? (1 - tx) : (-tx));
            bool ok = rok && (ix >= 0) && (ix < IW);
            size_t pos = (size_t)iy * IW + ix;
            int ktb = (ty * 2 + tx) * cpt;
            for (int ct = 0; ct < cpt; ++ct) {
                int cc = ct * 32 + quad * 8;
                half8 a = {};
                if (ok) a = *(const half8*)(in + pos * IC + cc);
                size_t bi = ((size_t)(pz * KT4 + ktb + ct) * NT + nt0) * 64 + lane;
#pragma unroll
                for (int s = 0; s < 4; ++s)
                    acc[s] = __builtin_amdgcn_mfma_f32_16x16x32_f16(a, bp[bi + s * 64], acc[s], 0, 0, 0);
            }
        }
    }
    int OW = IW * 2;
    int oy = 2 * a0 + py;
#pragma unroll
    for (int s = 0; s < 4; ++s) {
        int n = (nt0 + s) * 16 + l16;
        float bs = bias[n];
#pragma unroll
        for (int r = 0; r < 4; ++r) {
            int m = wave * 16 + quad * 4 + r;
            int ox = 2 * (b0 + m) + px;
            outb[((size_t)oy * OW + ox) * OC + n] = f2h(acc[s][r] + bs);
        }
    }
}

__global__ __launch_bounds__(256) void convout_mfma_kernel(
    const short* __restrict__ in, const short* __restrict__ Bp,
    const float* __restrict__ bias, float* __restrict__ out, int H, int W)
{
    int tid = threadIdx.x, wave = tid >> 6, lane = tid & 63;
    int quad = lane >> 4, l16 = lane & 15;
    int x0 = blockIdx.x * 64, y = blockIdx.y;
    const int C = 64, cpt = 2;
    const half8* bp = (const half8*)Bp;
    floatx4 acc = {0,0,0,0};
    int xm = x0 + wave * 16 + l16;
    for (int ky = 0; ky < 3; ++ky) {
        int yy = y + ky - 1;
        bool rok = (yy >= 0) && (yy < H);
        for (int kx = 0; kx < 3; ++kx) {
            int xx = xm + kx - 1;
            bool ok = rok && (xx >= 0) && (xx < W);
            size_t pos = (size_t)yy * W + xx;
            int ktb = (ky * 3 + kx) * cpt;
#pragma unroll
            for (int ct = 0; ct < cpt; ++ct) {
                int cc = ct * 32 + quad * 8;
                half8 a = {};
                if (ok) a = *(const half8*)(in + pos * C + cc);
                acc = __builtin_amdgcn_mfma_f32_16x16x32_f16(
                          a, bp[(size_t)(ktb + ct) * 64 + lane], acc, 0, 0, 0);
            }
        }
    }
    int oc = l16;
    if (oc < 3) {
        float bs = bias[oc];
#pragma unroll
        for (int r = 0; r < 4; ++r) {
            int m = wave * 16 + quad * 4 + r;
            int x = x0 + m;
            float v = acc[r] + bs;
            out[(size_t)oc * H * W + (size_t)y * W + x] = 1.f / (1.f + expf(-v));
        }
    }
}

// ============================================================================
extern "C" void kernel_launch(void* const* d_in, const int* in_sizes, int n_in,
                              void* d_out, int out_size, void* d_ws, size_t ws_size,
                              hipStream_t stream)
{
    const float* burst   = (const float*)d_in[0];
    const float* conv1_w = (const float*)d_in[1];  const float* conv1_b = (const float*)d_in[2];
    const float* conv2_w = (const float*)d_in[3];  const float* conv2_b = (const float*)d_in[4];
    const float* conv3_w = (const float*)d_in[5];  const float* conv3_b = (const float*)d_in[6];
    const float* ln1_g   = (const float*)d_in[7];  const float* ln1_b   = (const float*)d_in[8];
    const float* Wqk     = (const float*)d_in[9];  const float* bqk     = (const float*)d_in[10];
    const float* Wv      = (const float*)d_in[11]; const float* bvv     = (const float*)d_in[12];
    const float* Wo      = (const float*)d_in[13]; const float* bo      = (const float*)d_in[14];
    const float* rot     = (const float*)d_in[15];
    const float* ln2_g   = (const float*)d_in[16]; const float* ln2_b   = (const float*)d_in[17];
    const float* Wff1    = (const float*)d_in[18]; const float* bff1    = (const float*)d_in[19];
    const float* Wff2    = (const float*)d_in[20]; const float* bff2    = (const float*)d_in[21];
    const float* up1_w   = (const float*)d_in[22]; const float* up1_b   = (const float*)d_in[23];
    const float* dec1_w  = (const float*)d_in[24]; const float* dec1_b  = (const float*)d_in[25];
    const float* up2_w   = (const float*)d_in[26]; const float* up2_b   = (const float*)d_in[27];
    const float* dec2_w  = (const float*)d_in[28]; const float* dec2_b  = (const float*)d_in[29];
    const float* out_w   = (const float*)d_in[30]; const float* out_b   = (const float*)d_in[31];

    float* ws = (float*)d_ws;
    // persistent regions (fl offsets)
    short* e1h = (short*)(ws + 0);          // 4.19M sh
    short* e2h = (short*)(ws + 2097152);    // 2.1M sh
    float* seq = ws + 3145728;
    float* qkb = ws + 4194304;
    float* vvb = ws + 5242880;
    float* knb = ws + 6291456;
    int* buckets = (int*)(ws + 6307840);
    int* perm    = (int*)(ws + 6324224);
    short* xn0 = (short*)(ws + 6340608);    // 1.05M sh each (also oo planes)
    short* xn1 = (short*)(ws + 6864896);
    short* xn2 = (short*)(ws + 7389184);
    short* hdn0 = (short*)(ws + 7913472);   // 4.19M sh each
    short* hdn1 = (short*)(ws + 10010624);
    short* hdn2 = (short*)(ws + 12107776);
    // per-layer weight packs
    short* pqk0 = (short*)(ws + 14204928); short* pqk1 = (short*)(ws + 14237696); short* pqk2 = (short*)(ws + 14270464);
    short* pv0  = (short*)(ws + 14303232); short* pv1  = (short*)(ws + 14336000); short* pv2  = (short*)(ws + 14368768);
    short* po0  = (short*)(ws + 14401536); short* po1  = (short*)(ws + 14434304); short* po2  = (short*)(ws + 14467072);
    short* pf10 = (short*)(ws + 14499840); short* pf11 = (short*)(ws + 14630912); short* pf12 = (short*)(ws + 14761984);
    short* pf20 = (short*)(ws + 14893056); short* pf21 = (short*)(ws + 15024128); short* pf22 = (short*)(ws + 15155200);
    // decoder packs
    short* pdec1 = (short*)(ws + 15286272);
    short* pdec2 = (short*)(ws + 15433728);
    short* pout  = (short*)(ws + 15470592);
    short* pup1  = (short*)(ws + 15475200);
    short* pup2  = (short*)(ws + 15737344);   // end 15802880 fl = 60.3 MiB
    // encoder overlays
    float* e1f = ws + 7913472;                // inside hdn region
    short* p1_0 = (short*)(ws + 12107776); short* p1_1 = (short*)(ws + 12632064); short* p1_2 = (short*)(ws + 13156352);
    short* p2_0 = (short*)(ws + 13680640); short* p2_1 = (short*)(ws + 13942784); short* p2_2 = (short*)(ws + 14204928);
    short* pc2_0 = (short*)(ws + 14467072); short* pc2_1 = (short*)(ws + 14503936); short* pc2_2 = (short*)(ws + 14540800);
    short* pc3_0 = (short*)(ws + 14577664); short* pc3_1 = (short*)(ws + 14725120); short* pc3_2 = (short*)(ws + 14872576);
    short* e2_0 = (short*)(ws + 4194304); short* e2_1 = (short*)(ws + 5242880); short* e2_2 = (short*)(ws + 6291456);
    // decoder overlays (hdn region dead)
    short* seqh = (short*)(ws + 7913472);
    short* d1   = (short*)(ws + 8437760);
    short* d1c  = (short*)(ws + 9486336);
    short* d2   = (short*)(ws + 10534912);
    short* d2c  = (short*)(ws + 12632064);

    dim3 b16(16, 16);

    // ---- static packs
    pack_conv3_kernel<<<36, 256, 0, stream>>>(conv2_w, pc2_0, pc2_1, pc2_2, 64, 128, 9216);
    pack_conv3_kernel<<<144, 256, 0, stream>>>(conv3_w, pc3_0, pc3_1, pc3_2, 128, 256, 36864);
    pack_conv_kernel<<<144, 256, 0, stream>>>(dec1_w, pdec1, 256, 128, 8, 36864);
    pack_conv_kernel<<<36, 256, 0, stream>>>(dec2_w, pdec2, 128, 64, 4, 9216);
    pack_conv_kernel<<<5, 256, 0, stream>>>(out_w, pout, 64, 3, 1, 1152);
    pack_convt_kernel<<<256, 256, 0, stream>>>(up1_w, pup1, 256, 128, 65536);
    pack_convt_kernel<<<64, 256, 0, stream>>>(up2_w, pup2, 128, 64, 16384);

    // ---- encoder
    conv1_nhwc_kernel<8><<<dim3(16, 16, 8), b16, 0, stream>>>(
        burst, conv1_w, conv1_b, e1f, e1h, 256, 256, 64);
    maxpool1_bf3_kernel<<<1024, 256, 0, stream>>>(e1f, p1_0, p1_1, p1_2, 128, 256, 64);
    conv_bf3_kernel<<<dim3(2, 128, 2), 256, 0, stream>>>(
        p1_0, p1_1, p1_2, pc2_0, pc2_1, pc2_2, conv2_b,
        nullptr, e2_0, e2_1, e2_2, e2h, 128, 128, 64, 128);
    maxpool2_bf3_kernel<<<512, 256, 0, stream>>>(
        e2_0, e2_1, e2_2, p2_0, p2_1, p2_2, 64, 128, 128);
    conv_bf3_kernel<<<dim3(1, 64, 4), 256, 0, stream>>>(
        p2_0, p2_1, p2_2, pc3_0, pc3_1, pc3_2, conv3_b,
        seq, nullptr, nullptr, nullptr, nullptr, 64, 64, 128, 256);

    // ---- reformer, 4 layers (bf16x3 MFMA)
    for (int i = 0; i < 4; ++i) {
        pack_layer_kernel<<<352, 256, 0, stream>>>(
            Wqk + i * 65536, Wv + i * 65536, Wo + i * 65536,
            Wff1 + i * 262144, Wff2 + i * 262144,
            pqk0, pqk1, pqk2, pv0, pv1, pv2, po0, po1, po2,
            pf10, pf11, pf12, pf20, pf21, pf22);
        ln_bf3_kernel<<<1024, 256, 0, stream>>>(seq, ln1_g + i * 256, ln1_b + i * 256,
                                                xn0, xn1, xn2);
        gemm_qkv_bf3_kernel<<<dim3(16, 64), 256, 0, stream>>>(
            xn0, xn1, xn2, pqk0, pqk1, pqk2, bqk + i * 256, qkb,
            pv0, pv1, pv2, bvv + i * 256, vvb, 256);
        bucketn_kernel<<<64, 256, 0, stream>>>(qkb, rot + i * 8192, buckets, knb);
        lsh_sort_kernel<<<4, 256, 0, stream>>>(buckets, perm);
        attn_kernel<<<dim3(64, 4, 2), 256, 0, stream>>>(qkb, vvb, knb, perm, xn0, xn1, xn2);
        gemm_bf3_kernel<<<dim3(8, 64), 256, 0, stream>>>(
            xn0, xn1, xn2, po0, po1, po2, bo + i * 256, seq,
            nullptr, nullptr, nullptr, nullptr, 256, 256, 0, 1);
        ln_bf3_kernel<<<1024, 256, 0, stream>>>(seq, ln2_g + i * 256, ln2_b + i * 256,
                                                xn0, xn1, xn2);
        gemm_bf3_kernel<<<dim3(32, 64), 256, 0, stream>>>(
            xn0, xn1, xn2, pf10, pf11, pf12, bff1 + i * 1024, nullptr,
            hdn0, hdn1, hdn2, nullptr, 1024, 256, 1, 0);
        gemm_bf3_kernel<<<dim3(8, 64), 256, 0, stream>>>(
            hdn0, hdn1, hdn2, pf20, pf21, pf22, bff2 + i * 256, seq,
            nullptr, nullptr, nullptr, (i == 3) ? seqh : nullptr, 256, 1024, 0, 1);
    }

    // ---- decoder (plain fp16 MFMA)
    convt_mfma_kernel<<<dim3(1, 64, 8), 256, 0, stream>>>(
        seqh, 256, pup1, up1_b, d1, 64, 64, 128);
    conv_mfma_kernel<<<dim3(2, 128, 2), 256, 0, stream>>>(
        d1, 128, e2h, 128, pdec1, dec1_b, d1c, 128, 128, 128);
    convt_mfma_kernel<<<dim3(2, 128, 4), 256, 0, stream>>>(
        d1c, 128, pup2, up2_b, d2, 128, 128, 64);
    conv_mfma_kernel<<<dim3(4, 256, 1), 256, 0, stream>>>(
        d2, 64, e1h, 64, pdec2, dec2_b, d2c, 256, 256, 64);
    convout_mfma_kernel<<<dim3(4, 256), 256, 0, stream>>>(
        d2c, pout, out_b, (float*)d_out, 256, 256);
}

// Round 12
// 1203.398 us; speedup vs baseline: 1.1459x; 1.0978x over previous
//
#include <hip/hip_runtime.h>
#include <hip/hip_bf16.h>
#include <math.h>

using short8  = __attribute__((ext_vector_type(8))) short;
using half8   = __attribute__((ext_vector_type(8))) _Float16;
using floatx4 = __attribute__((ext_vector_type(4))) float;

static __device__ __forceinline__ float gelu_f(float x) {
    float x3 = x * x * x;
    return 0.5f * x * (1.f + tanhf(0.7978845608028654f * (x + 0.044715f * x3)));
}
static __device__ __forceinline__ short f2h(float f) {
    _Float16 h = (_Float16)f;
    return __builtin_bit_cast(short, h);
}
static __device__ __forceinline__ short f2bf(float f) {
    unsigned u = __float_as_uint(f);
    u += 0x7fffu + ((u >> 16) & 1u);   // RNE
    return (short)(u >> 16);
}
static __device__ __forceinline__ float bf2f(short s) {
    return __uint_as_float(((unsigned)(unsigned short)s) << 16);
}
struct bf3s { short a, b, c; };
static __device__ __forceinline__ bf3s split3(float v) {
    short c0 = f2bf(v); float r = v - bf2f(c0);
    short c1 = f2bf(r); r -= bf2f(c1);
    short c2 = f2bf(r);
    bf3s s; s.a = c0; s.b = c1; s.c = c2; return s;
}

// ============================================================================
// conv1 (C=3): fp32 direct, NHWC fp32 out + fp16 dual write
// ============================================================================
template <int OCB>
__global__ __launch_bounds__(256) void conv1_nhwc_kernel(
    const float* __restrict__ in1, const float* __restrict__ w,
    const float* __restrict__ bias, float* __restrict__ out,
    short* __restrict__ outh, int H, int W, int OC)
{
    int tx = threadIdx.x, ty = threadIdx.y;
    int x = blockIdx.x * 16 + tx, y = blockIdx.y * 16 + ty;
    int oc0 = blockIdx.z * OCB;
    const int C = 3;
    float acc[OCB];
#pragma unroll
    for (int o = 0; o < OCB; ++o) acc[o] = 0.f;
    for (int ic = 0; ic < C; ++ic) {
        const float* src = in1 + (size_t)ic * H * W;
        float v[9];
#pragma unroll
        for (int ky = 0; ky < 3; ++ky) {
            int iy = y + ky - 1;
            bool okY = (iy >= 0) && (iy < H);
#pragma unroll
            for (int kx = 0; kx < 3; ++kx) {
                int ix = x + kx - 1;
                bool ok = okY && (ix >= 0) && (ix < W);
                v[ky * 3 + kx] = ok ? src[(size_t)iy * W + ix] : 0.f;
            }
        }
        const float* wp = w + ((size_t)oc0 * C + ic) * 9;
#pragma unroll
        for (int o = 0; o < OCB; ++o) {
            const float* wo = wp + (size_t)o * C * 9;
            acc[o] += v[0]*wo[0] + v[1]*wo[1] + v[2]*wo[2]
                    + v[3]*wo[3] + v[4]*wo[4] + v[5]*wo[5]
                    + v[6]*wo[6] + v[7]*wo[7] + v[8]*wo[8];
        }
    }
    size_t ob = ((size_t)y * W + x) * OC + oc0;
#pragma unroll
    for (int o = 0; o < OCB; ++o) {
        float r = fmaxf(acc[o] + bias[oc0 + o], 0.f);
        out[ob + o] = r;
        outh[ob + o] = f2h(r);
    }
}

// ============================================================================
// maxpools with bf16x3 split outputs (NHWC)
// ============================================================================
__global__ __launch_bounds__(256) void maxpool1_bf3_kernel(
    const float* __restrict__ in, short* __restrict__ o0, short* __restrict__ o1,
    short* __restrict__ o2, int OW, int IW, int C)
{
    int idx = blockIdx.x * 256 + threadIdx.x;
    int g = idx % (C >> 2); int p = idx / (C >> 2);
    int x = p % OW; int y = p / OW;
    size_t base = ((size_t)(2 * y) * IW + 2 * x) * C + g * 4;
    float4 a = *(const float4*)(in + base);
    float4 b = *(const float4*)(in + base + C);
    float4 c = *(const float4*)(in + base + (size_t)IW * C);
    float4 d = *(const float4*)(in + base + (size_t)IW * C + C);
    float v[4];
    v[0] = fmaxf(fmaxf(a.x, b.x), fmaxf(c.x, d.x));
    v[1] = fmaxf(fmaxf(a.y, b.y), fmaxf(c.y, d.y));
    v[2] = fmaxf(fmaxf(a.z, b.z), fmaxf(c.z, d.z));
    v[3] = fmaxf(fmaxf(a.w, b.w), fmaxf(c.w, d.w));
    size_t o = (size_t)p * C + g * 4;
#pragma unroll
    for (int j = 0; j < 4; ++j) {
        bf3s s = split3(v[j]);
        o0[o + j] = s.a; o1[o + j] = s.b; o2[o + j] = s.c;
    }
}

__global__ __launch_bounds__(256) void maxpool2_bf3_kernel(
    const short* __restrict__ i0, const short* __restrict__ i1,
    const short* __restrict__ i2, short* __restrict__ o0, short* __restrict__ o1,
    short* __restrict__ o2, int OW, int IW, int C)
{
    int idx = blockIdx.x * 256 + threadIdx.x;
    int g = idx % (C >> 2); int p = idx / (C >> 2);
    int x = p % OW; int y = p / OW;
    float v[4] = {-1e30f, -1e30f, -1e30f, -1e30f};
#pragma unroll
    for (int dy = 0; dy < 2; ++dy)
#pragma unroll
        for (int dx = 0; dx < 2; ++dx) {
            size_t base = ((size_t)(2 * y + dy) * IW + 2 * x + dx) * C + g * 4;
#pragma unroll
            for (int j = 0; j < 4; ++j) {
                float u = bf2f(i0[base + j]) + bf2f(i1[base + j]) + bf2f(i2[base + j]);
                v[j] = fmaxf(v[j], u);
            }
        }
    size_t o = (size_t)p * C + g * 4;
#pragma unroll
    for (int j = 0; j < 4; ++j) {
        bf3s s = split3(v[j]);
        o0[o + j] = s.a; o1[o + j] = s.b; o2[o + j] = s.c;
    }
}

// ============================================================================
// pack conv weights -> 3 bf16 planes, k = (ky*3+kx)*C + c
// ============================================================================
__global__ void pack_conv3_kernel(const float* __restrict__ w,
                                  short* __restrict__ B0, short* __restrict__ B1,
                                  short* __restrict__ B2, int C, int OC, int total)
{
    int t = blockIdx.x * 256 + threadIdx.x;
    if (t >= total) return;
    int lane = t & 63, fi = t >> 6;
    int NT = OC >> 4;
    int nt = fi % NT, kt = fi / NT;
    int cpt = C >> 5;
    int tap = kt / cpt, ct = kt % cpt;
    int c = ct * 32 + (lane >> 4) * 8;
    int oc = nt * 16 + (lane & 15);
    short8 v0, v1, v2;
#pragma unroll
    for (int j = 0; j < 8; ++j) {
        bf3s s = split3(w[((size_t)oc * C + c + j) * 9 + tap]);
        v0[j] = s.a; v1[j] = s.b; v2[j] = s.c;
    }
    ((short8*)B0)[t] = v0; ((short8*)B1)[t] = v1; ((short8*)B2)[t] = v2;
}

// ============================================================================
// bf16x3 implicit-GEMM 3x3 conv, LDS-staged input (v3).
// Per (plane, 64-ch chunk): stage 3 rows x 66 px into LDS, then 9 taps from LDS.
// Plane-major accumulation (reorder-class vs R9/R11 — same math).
// ============================================================================
__global__ __launch_bounds__(256) void conv_bf3_kernel(
    const short* __restrict__ ia0, const short* __restrict__ ia1,
    const short* __restrict__ ia2,
    const short* __restrict__ B0, const short* __restrict__ B1,
    const short* __restrict__ B2, const float* __restrict__ bias,
    float* __restrict__ outf, short* __restrict__ o0, short* __restrict__ o1,
    short* __restrict__ o2, short* __restrict__ oh,
    int H, int W, int C, int OC)
{
    __shared__ short sa[3 * 66 * 68];   // [row][x+1][ch(64)+4pad]
    int tid = threadIdx.x, wave = tid >> 6, lane = tid & 63;
    int quad = lane >> 4, l16 = lane & 15;
    int x0 = blockIdx.x * 64, y = blockIdx.y, nt0 = blockIdx.z * 4;
    int cpt = C >> 5, NT = OC >> 4;
    const short8* b0p = (const short8*)B0;
    const short8* b1p = (const short8*)B1;
    const short8* b2p = (const short8*)B2;
    const short* ia[3] = {ia0, ia1, ia2};
    floatx4 aM[4] = {{0,0,0,0},{0,0,0,0},{0,0,0,0},{0,0,0,0}};
    floatx4 aC[4] = {{0,0,0,0},{0,0,0,0},{0,0,0,0},{0,0,0,0}};
    int xl = wave * 16 + l16;   // 0..63
    for (int p = 0; p < 3; ++p) {
        const short* src_p = ia[p];
        for (int c0 = 0; c0 < C; c0 += 64) {
            __syncthreads();
            // stage 3 rows x 66 px x 64 ch (coalesced: ch8 fastest)
            for (int i = tid; i < 3 * 66 * 8; i += 256) {
                int ch8 = i & 7; int rem = i >> 3;
                int xx = rem % 66; int rr = rem / 66;
                int gy = y + rr - 1, gx = x0 + xx - 1;
                short8 v = {0,0,0,0,0,0,0,0};
                if (gy >= 0 && gy < H && gx >= 0 && gx < W)
                    v = *(const short8*)(src_p + ((size_t)gy * W + gx) * C + c0 + ch8 * 8);
                *(short8*)(sa + (rr * 66 + xx) * 68 + ch8 * 8) = v;
            }
            __syncthreads();
            for (int ky = 0; ky < 3; ++ky) {
                for (int kx = 0; kx < 3; ++kx) {
                    int ktb = (ky * 3 + kx) * cpt + (c0 >> 5);
#pragma unroll
                    for (int ct2 = 0; ct2 < 2; ++ct2) {
                        short8 A = *(const short8*)(
                            sa + (ky * 66 + xl + kx) * 68 + ct2 * 32 + quad * 8);
                        size_t bi = ((size_t)(ktb + ct2) * NT + nt0) * 64 + lane;
                        if (p == 0) {
#pragma unroll
                            for (int s = 0; s < 4; ++s) {
                                aM[s] = __builtin_amdgcn_mfma_f32_16x16x32_bf16(A, b0p[bi + s * 64], aM[s], 0, 0, 0);
                                aC[s] = __builtin_amdgcn_mfma_f32_16x16x32_bf16(A, b1p[bi + s * 64], aC[s], 0, 0, 0);
                                aC[s] = __builtin_amdgcn_mfma_f32_16x16x32_bf16(A, b2p[bi + s * 64], aC[s], 0, 0, 0);
                            }
                        } else if (p == 1) {
#pragma unroll
                            for (int s = 0; s < 4; ++s) {
                                aC[s] = __builtin_amdgcn_mfma_f32_16x16x32_bf16(A, b0p[bi + s * 64], aC[s], 0, 0, 0);
                                aC[s] = __builtin_amdgcn_mfma_f32_16x16x32_bf16(A, b1p[bi + s * 64], aC[s], 0, 0, 0);
                            }
                        } else {
#pragma unroll
                            for (int s = 0; s < 4; ++s)
                                aC[s] = __builtin_amdgcn_mfma_f32_16x16x32_bf16(A, b0p[bi + s * 64], aC[s], 0, 0, 0);
                        }
                    }
                }
            }
        }
    }
#pragma unroll
    for (int s = 0; s < 4; ++s) {
        int n = (nt0 + s) * 16 + l16;
        float bs = bias[n];
#pragma unroll
        for (int r = 0; r < 4; ++r) {
            int m = wave * 16 + quad * 4 + r;
            int x = x0 + m;
            float v = fmaxf(aM[s][r] + aC[s][r] + bs, 0.f);
            size_t o = ((size_t)y * W + x) * OC + n;
            if (outf) outf[o] = v;
            else {
                bf3s sp = split3(v);
                o0[o] = sp.a; o1[o] = sp.b; o2[o] = sp.c;
                oh[o] = f2h(v);
            }
        }
    }
}

// ============================================================================
// LayerNorm: fp32 math, bf16x3 plane outputs
// ============================================================================
__global__ __launch_bounds__(256) void ln_bf3_kernel(
    const float* __restrict__ x, const float* __restrict__ g,
    const float* __restrict__ b, short* __restrict__ y0,
    short* __restrict__ y1, short* __restrict__ y2)
{
    int wave = threadIdx.x >> 6, lane = threadIdx.x & 63;
    int n = blockIdx.x * 4 + wave;
    const float* xr = x + (size_t)n * 256;
    float4 v = *(const float4*)(xr + lane * 4);
    float s = v.x + v.y + v.z + v.w;
#pragma unroll
    for (int m = 1; m < 64; m <<= 1) s += __shfl_xor(s, m);
    float mean = s * (1.f / 256.f);
    float cx = v.x - mean, cy = v.y - mean, cz = v.z - mean, cw = v.w - mean;
    float q = cx * cx + cy * cy + cz * cz + cw * cw;
#pragma unroll
    for (int m = 1; m < 64; m <<= 1) q += __shfl_xor(q, m);
    float rstd = rsqrtf(q * (1.f / 256.f) + 1e-5f);
    float4 gv = *(const float4*)(g + lane * 4);
    float4 bv = *(const float4*)(b + lane * 4);
    float o[4];
    o[0] = cx * rstd * gv.x + bv.x;
    o[1] = cy * rstd * gv.y + bv.y;
    o[2] = cz * rstd * gv.z + bv.z;
    o[3] = cw * rstd * gv.w + bv.w;
    size_t ob = (size_t)n * 256 + lane * 4;
#pragma unroll
    for (int j = 0; j < 4; ++j) {
        bf3s sp = split3(o[j]);
        y0[ob + j] = sp.a; y1[ob + j] = sp.b; y2[ob + j] = sp.c;
    }
}

// ============================================================================
// fused bucket + knorm (fp32, bucket-critical). 64-thread blocks -> 256 blocks.
// ============================================================================
__global__ __launch_bounds__(64) void bucketn_kernel(
    const float* __restrict__ qk, const float* __restrict__ rot,
    int* __restrict__ buckets, float* __restrict__ knrm)
{
    int t = blockIdx.x * 64 + threadIdx.x;
    int h = t >> 12, n = t & 4095;
    const float* q = qk + (size_t)n * 256 + h * 64;
    const float* R = rot + (size_t)h * 2048;
    float acc[32];
#pragma unroll
    for (int r = 0; r < 32; ++r) acc[r] = 0.f;
    float s2 = 0.f;
    for (int d = 0; d < 64; ++d) {
        float qd = q[d];
        s2 += qd * qd;
        const float* Rd = R + d * 32;
#pragma unroll
        for (int r = 0; r < 32; ++r) acc[r] += qd * Rd[r];
    }
    knrm[t] = 1.f / (sqrtf(s2) + 1e-6f);
    float bvv = acc[0]; int best = 0;
#pragma unroll
    for (int j = 1; j < 64; ++j) {
        float val = (j < 32) ? acc[j] : -acc[j - 32];
        if (val > bvv) { bvv = val; best = j; }
    }
    buckets[t] = best;
}

// ============================================================================
// stable counting sort, 1024-thread blocks (16 waves), one block per head
// ============================================================================
__global__ __launch_bounds__(1024) void lsh_sort_kernel(
    const int* __restrict__ buckets, int* __restrict__ perm)
{
    int h = blockIdx.x;
    const int* bk = buckets + h * 4096;
    __shared__ unsigned long long mask[64][64];
    __shared__ int counts[64];
    __shared__ int offsets[64];
    __shared__ int wpre[64][64];
    int tid = threadIdx.x, wave = tid >> 6, lane = tid & 63;
    for (int w = wave * 4; w < wave * 4 + 4; ++w) {
        int bl = bk[w * 64 + lane];
        for (int b = 0; b < 64; ++b) {
            unsigned long long m = __ballot(bl == b);
            if (lane == b) mask[b][w] = m;
        }
    }
    __syncthreads();
    if (tid < 64) {
        int c = 0;
        for (int w = 0; w < 64; ++w) c += __popcll(mask[tid][w]);
        counts[tid] = c;
    }
    __syncthreads();
    if (tid == 0) {
        int a = 0;
        for (int b = 0; b < 64; ++b) { offsets[b] = a; a += counts[b]; }
    }
    __syncthreads();
    for (int b = wave * 4; b < wave * 4 + 4; ++b) {
        int c = __popcll(mask[b][lane]);
        int incl = c;
#pragma unroll
        for (int off = 1; off < 64; off <<= 1) {
            int nb = __shfl_up(incl, off);
            if (lane >= off) incl += nb;
        }
        wpre[b][lane] = incl - c + offsets[b];
    }
    __syncthreads();
    for (int i = tid; i < 4096; i += 1024) {
        int b = bk[i]; int w = i >> 6; int l = i & 63;
        unsigned long long below = mask[b][w] & ((1ull << l) - 1ull);
        int pos = wpre[b][w] + __popcll(below);
        perm[h * 4096 + pos] = i;
    }
}

// ============================================================================
// attention v2 (R11-proven): 32 rows/block, 8 threads/row, parallel softmax.
// ============================================================================
__global__ __launch_bounds__(256) void attn_kernel(
    const float* __restrict__ qk, const float* __restrict__ vv,
    const float* __restrict__ knrm, const int* __restrict__ perm,
    short* __restrict__ o0, short* __restrict__ o1, short* __restrict__ o2)
{
    __shared__ float ks[128 * 64];
    __shared__ float dotsT[128 * 32];
    __shared__ float pmax[8][32];
    __shared__ float psum[8][32];
    int c = blockIdx.x, h = blockIdx.y, rh = blockIdx.z;
    int tid = threadIdx.x;
    const int* pm = perm + h * 4096;
    int cm = (c + 63) & 63;
    {
        int jr = tid >> 1, hf = tid & 1;
        int sk = (jr < 64) ? (c * 64 + jr) : (cm * 64 + (jr - 64));
        int nk = pm[sk];
        float sc = knrm[h * 4096 + nk];
        const float* src = qk + (size_t)nk * 256 + h * 64 + hf * 32;
        float* dst = ks + jr * 64 + hf * 32;
#pragma unroll
        for (int d = 0; d < 32; d += 4) {
            float4 v = *(const float4*)(src + d);
            v.x *= sc; v.y *= sc; v.z *= sc; v.w *= sc;
            *(float4*)(dst + d) = v;
        }
    }
    __syncthreads();
    int rr = tid & 31, jq = tid >> 5;
    int r = rh * 32 + rr;
    int nq = pm[c * 64 + r];
    float mx = -1e30f;
    {
        float qreg[64];
        const float* src = qk + (size_t)nq * 256 + h * 64;
#pragma unroll
        for (int d = 0; d < 64; d += 4) {
            float4 v = *(const float4*)(src + d);
            qreg[d] = v.x; qreg[d + 1] = v.y; qreg[d + 2] = v.z; qreg[d + 3] = v.w;
        }
        for (int jj = 0; jj < 16; ++jj) {
            int j = jq * 16 + jj;
            const float* kr = ks + j * 64;
            float dot = 0.f;
#pragma unroll
            for (int d = 0; d < 64; d += 4) {
                float4 kv = *(const float4*)(kr + d);
                dot += qreg[d] * kv.x + qreg[d + 1] * kv.y
                     + qreg[d + 2] * kv.z + qreg[d + 3] * kv.w;
            }
            int sk = (j < 64) ? (c * 64 + j) : (cm * 64 + (j - 64));
            int nk = pm[sk];
            dot = (nk == nq) ? -1e5f : dot * 0.125f;
            dotsT[j * 32 + rr] = dot;
            mx = fmaxf(mx, dot);
        }
    }
    pmax[jq][rr] = mx;
    __syncthreads();
    float gmax = pmax[0][rr];
#pragma unroll
    for (int g = 1; g < 8; ++g) gmax = fmaxf(gmax, pmax[g][rr]);
    float ss = 0.f;
    for (int jj = 0; jj < 16; ++jj) {
        int j = jq * 16 + jj;
        float e = expf(dotsT[j * 32 + rr] - gmax);
        dotsT[j * 32 + rr] = e;
        ss += e;
    }
    psum[jq][rr] = ss;
    {
        int jr = tid >> 1, hf = tid & 1;
        int sk = (jr < 64) ? (c * 64 + jr) : (cm * 64 + (jr - 64));
        int nk = pm[sk];
        const float* src = vv + (size_t)nk * 256 + h * 64 + hf * 32;
        float* dst = ks + jr * 64 + hf * 32;
#pragma unroll
        for (int d = 0; d < 32; d += 4)
            *(float4*)(dst + d) = *(const float4*)(src + d);
    }
    __syncthreads();
    float tot = psum[0][rr];
#pragma unroll
    for (int g = 1; g < 8; ++g) tot += psum[g][rr];
    float inv = 1.f / tot;
    float acc[8] = {0.f, 0.f, 0.f, 0.f, 0.f, 0.f, 0.f, 0.f};
    for (int j = 0; j < 128; ++j) {
        float a = dotsT[j * 32 + rr];
        const float* vr = ks + j * 64 + jq * 8;
        float4 v0 = *(const float4*)(vr);
        float4 v1 = *(const float4*)(vr + 4);
        acc[0] += a * v0.x; acc[1] += a * v0.y; acc[2] += a * v0.z; acc[3] += a * v0.w;
        acc[4] += a * v1.x; acc[5] += a * v1.y; acc[6] += a * v1.z; acc[7] += a * v1.w;
    }
    size_t ob = (size_t)nq * 256 + h * 64 + jq * 8;
#pragma unroll
    for (int d = 0; d < 8; ++d) {
        bf3s sp = split3(acc[d] * inv);
        o0[ob + d] = sp.a; o1[ob + d] = sp.b; o2[ob + d] = sp.c;
    }
}

// ============================================================================
// fused per-layer weight pack: 5 matrices -> 15 bf16 fragment planes
// ============================================================================
static __device__ __forceinline__ void pack_one(
    const float* __restrict__ W, short* __restrict__ B0, short* __restrict__ B1,
    short* __restrict__ B2, int N, int t)
{
    int lane = t & 63, fi = t >> 6;
    int NT = N >> 4;
    int nt = fi % NT, kt = fi / NT;
    int n = nt * 16 + (lane & 15);
    int k0 = kt * 32 + (lane >> 4) * 8;
    short8 v0, v1, v2;
#pragma unroll
    for (int j = 0; j < 8; ++j) {
        bf3s s = split3(W[(size_t)(k0 + j) * N + n]);
        v0[j] = s.a; v1[j] = s.b; v2[j] = s.c;
    }
    ((short8*)B0)[t] = v0; ((short8*)B1)[t] = v1; ((short8*)B2)[t] = v2;
}

__global__ void pack_layer_kernel(
    const float* __restrict__ Wqk, const float* __restrict__ Wv,
    const float* __restrict__ Wo, const float* __restrict__ Wff1,
    const float* __restrict__ Wff2,
    short* q0, short* q1, short* q2, short* v0, short* v1, short* v2,
    short* o0, short* o1, short* o2, short* f10, short* f11, short* f12,
    short* f20, short* f21, short* f22)
{
    int t = blockIdx.x * 256 + threadIdx.x;
    if (t < 8192)       pack_one(Wqk, q0, q1, q2, 256, t);
    else if (t < 16384) pack_one(Wv, v0, v1, v2, 256, t - 8192);
    else if (t < 24576) pack_one(Wo, o0, o1, o2, 256, t - 16384);
    else if (t < 57344) pack_one(Wff1, f10, f11, f12, 1024, t - 24576);
    else if (t < 90112) pack_one(Wff2, f20, f21, f22, 256, t - 57344);
}

// ============================================================================
// bf16x3 GEMM v2 (R10): per-wave N=32, register prefetch, dual correction acc.
// ============================================================================
static __device__ __forceinline__ void gemm_bf3_core(
    const short* __restrict__ A0, const short* __restrict__ A1,
    const short* __restrict__ A2,
    const short* __restrict__ B0, const short* __restrict__ B1,
    const short* __restrict__ B2, const float* __restrict__ bias,
    float* __restrict__ Cf, short* __restrict__ D0, short* __restrict__ D1,
    short* __restrict__ D2, short* __restrict__ Dh,
    int N, int K, int act, int resid, int bx, int by)
{
    int tid = threadIdx.x, wave = tid >> 6, lane = tid & 63;
    int quad = lane >> 4, l16 = lane & 15;
    int m0 = by * 64 + wave * 16;
    int NT = N >> 4, nt0 = bx * 2;
    size_t arow = (size_t)(m0 + l16) * K + quad * 8;
    const short8* b0p = (const short8*)B0;
    const short8* b1p = (const short8*)B1;
    const short8* b2p = (const short8*)B2;
    floatx4 aM0 = {0,0,0,0}, aM1 = {0,0,0,0};
    floatx4 aC10 = {0,0,0,0}, aC11 = {0,0,0,0};
    floatx4 aC20 = {0,0,0,0}, aC21 = {0,0,0,0};
    int KT = K >> 5;
    size_t bi0 = (size_t)nt0 * 64 + lane;
    short8 a0 = *(const short8*)(A0 + arow);
    short8 a1 = *(const short8*)(A1 + arow);
    short8 a2 = *(const short8*)(A2 + arow);
    short8 w00 = b0p[bi0], w01 = b1p[bi0], w02 = b2p[bi0];
    short8 w10 = b0p[bi0 + 64], w11 = b1p[bi0 + 64], w12 = b2p[bi0 + 64];
    for (int kt = 0; kt < KT; ++kt) {
        short8 na0 = {}, na1 = {}, na2 = {};
        short8 nw00 = {}, nw01 = {}, nw02 = {}, nw10 = {}, nw11 = {}, nw12 = {};
        if (kt + 1 < KT) {
            size_t ar = arow + (size_t)(kt + 1) * 32;
            na0 = *(const short8*)(A0 + ar);
            na1 = *(const short8*)(A1 + ar);
            na2 = *(const short8*)(A2 + ar);
            size_t nbi = ((size_t)(kt + 1) * NT + nt0) * 64 + lane;
            nw00 = b0p[nbi]; nw01 = b1p[nbi]; nw02 = b2p[nbi];
            nw10 = b0p[nbi + 64]; nw11 = b1p[nbi + 64]; nw12 = b2p[nbi + 64];
        }
        aM0  = __builtin_amdgcn_mfma_f32_16x16x32_bf16(a0, w00, aM0, 0, 0, 0);
        aM1  = __builtin_amdgcn_mfma_f32_16x16x32_bf16(a0, w10, aM1, 0, 0, 0);
        aC10 = __builtin_amdgcn_mfma_f32_16x16x32_bf16(a0, w01, aC10, 0, 0, 0);
        aC11 = __builtin_amdgcn_mfma_f32_16x16x32_bf16(a0, w11, aC11, 0, 0, 0);
        aC20 = __builtin_amdgcn_mfma_f32_16x16x32_bf16(a1, w00, aC20, 0, 0, 0);
        aC21 = __builtin_amdgcn_mfma_f32_16x16x32_bf16(a1, w10, aC21, 0, 0, 0);
        aC10 = __builtin_amdgcn_mfma_f32_16x16x32_bf16(a0, w02, aC10, 0, 0, 0);
        aC11 = __builtin_amdgcn_mfma_f32_16x16x32_bf16(a0, w12, aC11, 0, 0, 0);
        aC20 = __builtin_amdgcn_mfma_f32_16x16x32_bf16(a1, w01, aC20, 0, 0, 0);
        aC21 = __builtin_amdgcn_mfma_f32_16x16x32_bf16(a1, w11, aC21, 0, 0, 0);
        aC10 = __builtin_amdgcn_mfma_f32_16x16x32_bf16(a2, w00, aC10, 0, 0, 0);
        aC11 = __builtin_amdgcn_mfma_f32_16x16x32_bf16(a2, w10, aC11, 0, 0, 0);
        a0 = na0; a1 = na1; a2 = na2;
        w00 = nw00; w01 = nw01; w02 = nw02;
        w10 = nw10; w11 = nw11; w12 = nw12;
    }
    floatx4 aM[2] = {aM0, aM1};
    floatx4 c1[2] = {aC10, aC11};
    floatx4 c2[2] = {aC20, aC21};
#pragma unroll
    for (int s = 0; s < 2; ++s) {
        int n = (nt0 + s) * 16 + l16;
        float bs = bias[n];
#pragma unroll
        for (int r = 0; r < 4; ++r) {
            int m = m0 + quad * 4 + r;
            float v = aM[s][r] + (c1[s][r] + c2[s][r]) + bs;
            if (act == 1) v = gelu_f(v);
            size_t o = (size_t)m * N + n;
            if (D0) {
                bf3s sp = split3(v);
                D0[o] = sp.a; D1[o] = sp.b; D2[o] = sp.c;
            } else {
                if (resid) v += Cf[o];
                Cf[o] = v;
                if (Dh) Dh[o] = f2h(v);
            }
        }
    }
}

__global__ __launch_bounds__(256) void gemm_bf3_kernel(
    const short* A0, const short* A1, const short* A2,
    const short* B0, const short* B1, const short* B2,
    const float* bias, float* Cf, short* D0, short* D1, short* D2, short* Dh,
    int N, int K, int act, int resid)
{
    gemm_bf3_core(A0, A1, A2, B0, B1, B2, bias, Cf, D0, D1, D2, Dh,
                  N, K, act, resid, blockIdx.x, blockIdx.y);
}

__global__ __launch_bounds__(256) void gemm_qkv_bf3_kernel(
    const short* A0, const short* A1, const short* A2,
    const short* Q0, const short* Q1, const short* Q2,
    const float* qb, float* Cq,
    const short* V0, const short* V1, const short* V2,
    const float* vb, float* Cv, int K)
{
    int side = blockIdx.x >> 3;
    gemm_bf3_core(A0, A1, A2, side ? V0 : Q0, side ? V1 : Q1, side ? V2 : Q2,
                  side ? vb : qb, side ? Cv : Cq, nullptr, nullptr, nullptr,
                  nullptr, 256, K, 0, 0, blockIdx.x & 7, blockIdx.y);
}

// ============================================================================
// plain fp16 MFMA decoder kernels (R8-proven)
// ============================================================================
__global__ void pack_conv_kernel(const float* __restrict__ w, short* __restrict__ Bp,
                                 int C, int OC, int NT, int total)
{
    int t = blockIdx.x * 256 + threadIdx.x;
    if (t >= total) return;
    int lane = t & 63, fi = t >> 6;
    int nt = fi % NT, kt = fi / NT;
    int cpt = C >> 5;
    int tap = kt / cpt, ct = kt % cpt;
    int c = ct * 32 + (lane >> 4) * 8;
    int oc = nt * 16 + (lane & 15);
    short8 v;
#pragma unroll
    for (int j = 0; j < 8; ++j) {
        float f = (oc < OC) ? w[((size_t)oc * C + c + j) * 9 + tap] : 0.f;
        v[j] = f2h(f);
    }
    ((short8*)Bp)[t] = v;
}

__global__ void pack_convt_kernel(const float* __restrict__ w, short* __restrict__ Bp,
                                  int IC, int OC, int total)
{
    int t = blockIdx.x * 256 + threadIdx.x;
    if (t >= total) return;
    int lane = t & 63, fi = t >> 6;
    int NT = OC >> 4, cpt = IC >> 5, KT4 = 4 * cpt;
    int nt = fi % NT, r = fi / NT;
    int kt = r % KT4, pz = r / KT4;
    int py = pz >> 1, px = pz & 1;
    int t4 = kt / cpt, ct = kt % cpt;
    int ty = t4 >> 1, tx = t4 & 1;
    int ky = py ? (2 * ty) : (1 + 2 * ty);
    int kx = px ? (2 * tx) : (1 + 2 * tx);
    int ic = ct * 32 + (lane >> 4) * 8;
    int oc = nt * 16 + (lane & 15);
    short8 v;
#pragma unroll
    for (int j = 0; j < 8; ++j)
        v[j] = f2h(w[(((size_t)(ic + j) * OC + oc) * 4 + ky) * 4 + kx]);
    ((short8*)Bp)[t] = v;
}

__global__ __launch_bounds__(256) void conv_mfma_kernel(
    const short* __restrict__ in1, int C1, const short* __restrict__ in2, int C2,
    const short* __restrict__ Bp, const float* __restrict__ bias,
    short* __restrict__ outb, int H, int W, int OC)
{
    int tid = threadIdx.x, wave = tid >> 6, lane = tid & 63;
    int quad = lane >> 4, l16 = lane & 15;
    int x0 = blockIdx.x * 64, y = blockIdx.y, nt0 = blockIdx.z * 4;
    int C = C1 + C2, cpt = C >> 5, NT = OC >> 4;
    const half8* bp = (const half8*)Bp;
    floatx4 acc[4] = {{0,0,0,0},{0,0,0,0},{0,0,0,0},{0,0,0,0}};
    int xm = x0 + wave * 16 + l16;
    for (int ky = 0; ky < 3; ++ky) {
        int yy = y + ky - 1;
        bool rok = (yy >= 0) && (yy < H);
        for (int kx = 0; kx < 3; ++kx) {
            int xx = xm + kx - 1;
            bool ok = rok && (xx >= 0) && (xx < W);
            size_t pos = (size_t)yy * W + xx;
            int ktb = (ky * 3 + kx) * cpt;
            for (int ct = 0; ct < cpt; ++ct) {
                int cc = ct * 32 + quad * 8;
                half8 a = {};
                if (ok) {
                    const short* src = (cc < C1) ? (in1 + pos * C1 + cc)
                                                 : (in2 + pos * C2 + (cc - C1));
                    a = *(const half8*)src;
                }
                size_t bi = ((size_t)(ktb + ct) * NT + nt0) * 64 + lane;
#pragma unroll
                for (int s = 0; s < 4; ++s)
                    acc[s] = __builtin_amdgcn_mfma_f32_16x16x32_f16(a, bp[bi + s * 64], acc[s], 0, 0, 0);
            }
        }
    }
#pragma unroll
    for (int s = 0; s < 4; ++s) {
        int n = (nt0 + s) * 16 + l16;
        float bs = bias[n];
#pragma unroll
        for (int r = 0; r < 4; ++r) {
            int m = wave * 16 + quad * 4 + r;
            int x = x0 + m;
            float v = fmaxf(acc[s][r] + bs, 0.f);
            outb[((size_t)y * W + x) * OC + n] = f2h(v);
        }
    }
}

__global__ __launch_bounds__(256) void convt_mfma_kernel(
    const short* __restrict__ in, int IC, const short* __restrict__ Bp,
    const float* __restrict__ bias, short* __restrict__ outb, int IH, int IW, int OC)
{
    int tid = threadIdx.x, wave = tid >> 6, lane = tid & 63;
    int quad = lane >> 4, l16 = lane & 15;
    int pz = blockIdx.z & 3, nt0 = (blockIdx.z >> 2) * 4;
    int py = pz >> 1, px = pz & 1;
    int a0 = blockIdx.y, b0 = blockIdx.x * 64;
    int cpt = IC >> 5, NT = OC >> 4, KT4 = 4 * cpt;
    const half8* bp = (const half8*)Bp;
    floatx4 acc[4] = {{0,0,0,0},{0,0,0,0},{0,0,0,0},{0,0,0,0}};
    int bm = b0 + wave * 16 + l16;
    for (int ty = 0; ty < 2; ++ty) {
        int iy = a0 + (py ? (1 - ty) : (-ty));
        bool rok = (iy >= 0) && (iy < IH);
        for (int tx = 0; tx < 2; ++tx) {
            int ix = bm + (px ? (1 - tx) : (-tx));
            bool ok = rok && (ix >= 0) && (ix < IW);
            size_t pos = (size_t)iy * IW + ix;
            int ktb = (ty * 2 + tx) * cpt;
            for (int ct = 0; ct < cpt; ++ct) {
                int cc = ct * 32 + quad * 8;
                half8 a = {};
                if (ok) a = *(const half8*)(in + pos * IC + cc);
                size_t bi = ((size_t)(pz * KT4 + ktb + ct) * NT + nt0) * 64 + lane;
#pragma unroll
                for (int s = 0; s < 4; ++s)
                    acc[s] = __builtin_amdgcn_mfma_f32_16x16x32_f16(a, bp[bi + s * 64], acc[s], 0, 0, 0);
            }
        }
    }
    int OW = IW * 2;
    int oy = 2 * a0 + py;
#pragma unroll
    for (int s = 0; s < 4; ++s) {
        int n = (nt0 + s) * 16 + l16;
        float bs = bias[n];
#pragma unroll
        for (int r = 0; r < 4; ++r) {
            int m = wave * 16 + quad * 4 + r;
            int ox = 2 * (b0 + m) + px;
            outb[((size_t)oy * OW + ox) * OC + n] = f2h(acc[s][r] + bs);
        }
    }
}

__global__ __launch_bounds__(256) void convout_mfma_kernel(
    const short* __restrict__ in, const short* __restrict__ Bp,
    const float* __restrict__ bias, float* __restrict__ out, int H, int W)
{
    int tid = threadIdx.x, wave = tid >> 6, lane = tid & 63;
    int quad = lane >> 4, l16 = lane & 15;
    int x0 = blockIdx.x * 64, y = blockIdx.y;
    const int C = 64, cpt = 2;
    const half8* bp = (const half8*)Bp;
    floatx4 acc = {0,0,0,0};
    int xm = x0 + wave * 16 + l16;
    for (int ky = 0; ky < 3; ++ky) {
        int yy = y + ky - 1;
        bool rok = (yy >= 0) && (yy < H);
        for (int kx = 0; kx < 3; ++kx) {
            int xx = xm + kx - 1;
            bool ok = rok && (xx >= 0) && (xx < W);
            size_t pos = (size_t)yy * W + xx;
            int ktb = (ky * 3 + kx) * cpt;
#pragma unroll
            for (int ct = 0; ct < cpt; ++ct) {
                int cc = ct * 32 + quad * 8;
                half8 a = {};
                if (ok) a = *(const half8*)(in + pos * C + cc);
                acc = __builtin_amdgcn_mfma_f32_16x16x32_f16(
                          a, bp[(size_t)(ktb + ct) * 64 + lane], acc, 0, 0, 0);
            }
        }
    }
    int oc = l16;
    if (oc < 3) {
        float bs = bias[oc];
#pragma unroll
        for (int r = 0; r < 4; ++r) {
            int m = wave * 16 + quad * 4 + r;
            int x = x0 + m;
            float v = acc[r] + bs;
            out[(size_t)oc * H * W + (size_t)y * W + x] = 1.f / (1.f + expf(-v));
        }
    }
}

// ============================================================================
extern "C" void kernel_launch(void* const* d_in, const int* in_sizes, int n_in,
                              void* d_out, int out_size, void* d_ws, size_t ws_size,
                              hipStream_t stream)
{
    const float* burst   = (const float*)d_in[0];
    const float* conv1_w = (const float*)d_in[1];  const float* conv1_b = (const float*)d_in[2];
    const float* conv2_w = (const float*)d_in[3];  const float* conv2_b = (const float*)d_in[4];
    const float* conv3_w = (const float*)d_in[5];  const float* conv3_b = (const float*)d_in[6];
    const float* ln1_g   = (const float*)d_in[7];  const float* ln1_b   = (const float*)d_in[8];
    const float* Wqk     = (const float*)d_in[9];  const float* bqk     = (const float*)d_in[10];
    const float* Wv      = (const float*)d_in[11]; const float* bvv     = (const float*)d_in[12];
    const float* Wo      = (const float*)d_in[13]; const float* bo      = (const float*)d_in[14];
    const float* rot     = (const float*)d_in[15];
    const float* ln2_g   = (const float*)d_in[16]; const float* ln2_b   = (const float*)d_in[17];
    const float* Wff1    = (const float*)d_in[18]; const float* bff1    = (const float*)d_in[19];
    const float* Wff2    = (const float*)d_in[20]; const float* bff2    = (const float*)d_in[21];
    const float* up1_w   = (const float*)d_in[22]; const float* up1_b   = (const float*)d_in[23];
    const float* dec1_w  = (const float*)d_in[24]; const float* dec1_b  = (const float*)d_in[25];
    const float* up2_w   = (const float*)d_in[26]; const float* up2_b   = (const float*)d_in[27];
    const float* dec2_w  = (const float*)d_in[28]; const float* dec2_b  = (const float*)d_in[29];
    const float* out_w   = (const float*)d_in[30]; const float* out_b   = (const float*)d_in[31];

    float* ws = (float*)d_ws;
    // persistent regions (fl offsets)
    short* e1h = (short*)(ws + 0);          // 4.19M sh
    short* e2h = (short*)(ws + 2097152);    // 2.1M sh
    float* seq = ws + 3145728;
    float* qkb = ws + 4194304;
    float* vvb = ws + 5242880;
    float* knb = ws + 6291456;
    int* buckets = (int*)(ws + 6307840);
    int* perm    = (int*)(ws + 6324224);
    short* xn0 = (short*)(ws + 6340608);
    short* xn1 = (short*)(ws + 6864896);
    short* xn2 = (short*)(ws + 7389184);
    short* hdn0 = (short*)(ws + 7913472);
    short* hdn1 = (short*)(ws + 10010624);
    short* hdn2 = (short*)(ws + 12107776);
    // per-layer weight packs
    short* pqk0 = (short*)(ws + 14204928); short* pqk1 = (short*)(ws + 14237696); short* pqk2 = (short*)(ws + 14270464);
    short* pv0  = (short*)(ws + 14303232); short* pv1  = (short*)(ws + 14336000); short* pv2  = (short*)(ws + 14368768);
    short* po0  = (short*)(ws + 14401536); short* po1  = (short*)(ws + 14434304); short* po2  = (short*)(ws + 14467072);
    short* pf10 = (short*)(ws + 14499840); short* pf11 = (short*)(ws + 14630912); short* pf12 = (short*)(ws + 14761984);
    short* pf20 = (short*)(ws + 14893056); short* pf21 = (short*)(ws + 15024128); short* pf22 = (short*)(ws + 15155200);
    // decoder packs
    short* pdec1 = (short*)(ws + 15286272);
    short* pdec2 = (short*)(ws + 15433728);
    short* pout  = (short*)(ws + 15470592);
    short* pup1  = (short*)(ws + 15475200);
    short* pup2  = (short*)(ws + 15737344);
    // encoder overlays
    float* e1f = ws + 7913472;
    short* p1_0 = (short*)(ws + 12107776); short* p1_1 = (short*)(ws + 12632064); short* p1_2 = (short*)(ws + 13156352);
    short* p2_0 = (short*)(ws + 13680640); short* p2_1 = (short*)(ws + 13942784); short* p2_2 = (short*)(ws + 14204928);
    short* pc2_0 = (short*)(ws + 14467072); short* pc2_1 = (short*)(ws + 14503936); short* pc2_2 = (short*)(ws + 14540800);
    short* pc3_0 = (short*)(ws + 14577664); short* pc3_1 = (short*)(ws + 14725120); short* pc3_2 = (short*)(ws + 14872576);
    short* e2_0 = (short*)(ws + 4194304); short* e2_1 = (short*)(ws + 5242880); short* e2_2 = (short*)(ws + 6291456);
    // decoder overlays
    short* seqh = (short*)(ws + 7913472);
    short* d1   = (short*)(ws + 8437760);
    short* d1c  = (short*)(ws + 9486336);
    short* d2   = (short*)(ws + 10534912);
    short* d2c  = (short*)(ws + 12632064);

    dim3 b16(16, 16);

    // ---- static packs
    pack_conv3_kernel<<<36, 256, 0, stream>>>(conv2_w, pc2_0, pc2_1, pc2_2, 64, 128, 9216);
    pack_conv3_kernel<<<144, 256, 0, stream>>>(conv3_w, pc3_0, pc3_1, pc3_2, 128, 256, 36864);
    pack_conv_kernel<<<144, 256, 0, stream>>>(dec1_w, pdec1, 256, 128, 8, 36864);
    pack_conv_kernel<<<36, 256, 0, stream>>>(dec2_w, pdec2, 128, 64, 4, 9216);
    pack_conv_kernel<<<5, 256, 0, stream>>>(out_w, pout, 64, 3, 1, 1152);
    pack_convt_kernel<<<256, 256, 0, stream>>>(up1_w, pup1, 256, 128, 65536);
    pack_convt_kernel<<<64, 256, 0, stream>>>(up2_w, pup2, 128, 64, 16384);

    // ---- encoder
    conv1_nhwc_kernel<8><<<dim3(16, 16, 8), b16, 0, stream>>>(
        burst, conv1_w, conv1_b, e1f, e1h, 256, 256, 64);
    maxpool1_bf3_kernel<<<1024, 256, 0, stream>>>(e1f, p1_0, p1_1, p1_2, 128, 256, 64);
    conv_bf3_kernel<<<dim3(2, 128, 2), 256, 0, stream>>>(
        p1_0, p1_1, p1_2, pc2_0, pc2_1, pc2_2, conv2_b,
        nullptr, e2_0, e2_1, e2_2, e2h, 128, 128, 64, 128);
    maxpool2_bf3_kernel<<<512, 256, 0, stream>>>(
        e2_0, e2_1, e2_2, p2_0, p2_1, p2_2, 64, 128, 128);
    conv_bf3_kernel<<<dim3(1, 64, 4), 256, 0, stream>>>(
        p2_0, p2_1, p2_2, pc3_0, pc3_1, pc3_2, conv3_b,
        seq, nullptr, nullptr, nullptr, nullptr, 64, 64, 128, 256);

    // ---- reformer, 4 layers (bf16x3 MFMA)
    for (int i = 0; i < 4; ++i) {
        pack_layer_kernel<<<352, 256, 0, stream>>>(
            Wqk + i * 65536, Wv + i * 65536, Wo + i * 65536,
            Wff1 + i * 262144, Wff2 + i * 262144,
            pqk0, pqk1, pqk2, pv0, pv1, pv2, po0, po1, po2,
            pf10, pf11, pf12, pf20, pf21, pf22);
        ln_bf3_kernel<<<1024, 256, 0, stream>>>(seq, ln1_g + i * 256, ln1_b + i * 256,
                                                xn0, xn1, xn2);
        gemm_qkv_bf3_kernel<<<dim3(16, 64), 256, 0, stream>>>(
            xn0, xn1, xn2, pqk0, pqk1, pqk2, bqk + i * 256, qkb,
            pv0, pv1, pv2, bvv + i * 256, vvb, 256);
        bucketn_kernel<<<256, 64, 0, stream>>>(qkb, rot + i * 8192, buckets, knb);
        lsh_sort_kernel<<<4, 1024, 0, stream>>>(buckets, perm);
        attn_kernel<<<dim3(64, 4, 2), 256, 0, stream>>>(qkb, vvb, knb, perm, xn0, xn1, xn2);
        gemm_bf3_kernel<<<dim3(8, 64), 256, 0, stream>>>(
            xn0, xn1, xn2, po0, po1, po2, bo + i * 256, seq,
            nullptr, nullptr, nullptr, nullptr, 256, 256, 0, 1);
        ln_bf3_kernel<<<1024, 256, 0, stream>>>(seq, ln2_g + i * 256, ln2_b + i * 256,
                                                xn0, xn1, xn2);
        gemm_bf3_kernel<<<dim3(32, 64), 256, 0, stream>>>(
            xn0, xn1, xn2, pf10, pf11, pf12, bff1 + i * 1024, nullptr,
            hdn0, hdn1, hdn2, nullptr, 1024, 256, 1, 0);
        gemm_bf3_kernel<<<dim3(8, 64), 256, 0, stream>>>(
            hdn0, hdn1, hdn2, pf20, pf21, pf22, bff2 + i * 256, seq,
            nullptr, nullptr, nullptr, (i == 3) ? seqh : nullptr, 256, 1024, 0, 1);
    }

    // ---- decoder (plain fp16 MFMA)
    convt_mfma_kernel<<<dim3(1, 64, 8), 256, 0, stream>>>(
        seqh, 256, pup1, up1_b, d1, 64, 64, 128);
    conv_mfma_kernel<<<dim3(2, 128, 2), 256, 0, stream>>>(
        d1, 128, e2h, 128, pdec1, dec1_b, d1c, 128, 128, 128);
    convt_mfma_kernel<<<dim3(2, 128, 4), 256, 0, stream>>>(
        d1c, 128, pup2, up2_b, d2, 128, 128, 64);
    conv_mfma_kernel<<<dim3(4, 256, 1), 256, 0, stream>>>(
        d2, 64, e1h, 64, pdec2, dec2_b, d2c, 256, 256, 64);
    convout_mfma_kernel<<<dim3(4, 256), 256, 0, stream>>>(
        d2c, pout, out_b, (float*)d_out, 256, 256);
}